// Round 2
// baseline (1020.065 us; speedup 1.0000x reference)
//
#include <hip/hip_runtime.h>
#include <math.h>

__device__ __forceinline__ float eluf(float v) { return v > 0.f ? v : expm1f(v); }
__device__ __forceinline__ float geluf(float v) {
  return 0.5f * v * (1.f + erff(v * 0.70710678118654752f));
}

#define BN_S 0.99999500003749969f   /* 1/sqrt(1+1e-5) */

// ============================================================
// k_tws1: tws1[i][u] = s1[i] * tw_g[i%32][u-32+P_g]  (0 outside window)
//         c1[i]     = s1[i]*tb[i] + bn1_b[i]
// All four temporal kernels are symmetric (kw = 2P+1), common u in [-32,32].
// ============================================================
__global__ void k_tws1(const float* tw1, const float* tw2, const float* tw3, const float* tw4,
                       const float* tb1, const float* tb2, const float* tb3, const float* tb4,
                       const float* bn1g, const float* bn1b,
                       float* tws1, float* c1) {
  int idx = blockIdx.x * 256 + threadIdx.x;
  if (idx < 8320) {
    int i = idx / 65, u = idx - i * 65;
    int g = i >> 5, il = i & 31;
    const float* tws[4] = {tw1, tw2, tw3, tw4};
    const int P[4] = {7, 12, 25, 32};
    int c = u - 32;
    float s1 = bn1g[i] * BN_S;
    float val = 0.f;
    int p = P[g];
    if (c >= -p && c <= p) val = s1 * tws[g][il * (2 * p + 1) + (c + p)];
    tws1[idx] = val;
  } else if (idx < 8448) {
    int i = idx - 8320;
    int g = i >> 5, il = i & 31;
    const float* tbs[4] = {tb1, tb2, tb3, tb4};
    float s1 = bn1g[i] * BN_S;
    c1[i] = s1 * tbs[g][il] + bn1b[i];
  }
}

// ============================================================
// k_weff: Wt[(kh*65+u)*128 + o] = sum_i sw[o,i,kh] * tws1[i][u]
//         biasEff[o] = sb[o] + sum_{i,kh} sw[o,i,kh]*c1[i]
// one block per o (128 blocks)
// ============================================================
__global__ __launch_bounds__(256) void k_weff(const float* __restrict__ sw, const float* __restrict__ sb,
                                              const float* __restrict__ tws1, const float* __restrict__ c1,
                                              float* __restrict__ Wt, float* __restrict__ biasEff) {
  __shared__ float red[256];
  int o = blockIdx.x, tid = threadIdx.x;
  const float* swo = sw + o * 8192;   // sw[o][i][kh], i-major (128x64)
  for (int idx = tid; idx < 4160; idx += 256) {
    int kh = idx / 65, u = idx - kh * 65;
    float a = 0.f;
    #pragma unroll 4
    for (int i = 0; i < 128; i++)
      a = fmaf(swo[i * 64 + kh], tws1[i * 65 + u], a);
    Wt[idx * 128 + o] = a;
  }
  float pa = 0.f;
  for (int j = tid; j < 8192; j += 256)
    pa = fmaf(swo[j], c1[j >> 6], pa);
  red[tid] = pa;
  __syncthreads();
  for (int s = 128; s > 0; s >>= 1) {
    if (tid < s) red[tid] += red[tid + s];
    __syncthreads();
  }
  if (tid == 0) biasEff[o] = red[0] + sb[o];
}

// ============================================================
// k_conv: fused (temporal+spatial) conv + bn2 + elu
//   z[b][o][t] = elu( s2[o]*(sum_{kh,u} Wt[kh][u][o]*x[b][kh][t+u-32] + biasEff[o]) + b2[o] )
// grid (4 t-tiles of 256, 8 o-tiles of 16, 16 b), 256 threads (t per thread).
// ============================================================
__global__ __launch_bounds__(256) void k_conv(const float* __restrict__ x,
                                              const float* __restrict__ Wt,
                                              const float* __restrict__ biasEff,
                                              const float* __restrict__ bn2g, const float* __restrict__ bn2b,
                                              float* __restrict__ z) {
  __shared__ float xs[32 * 320];
  const int tt = threadIdx.x;
  const int t0 = blockIdx.x * 256;
  const int o0 = blockIdx.y * 16;
  const int b  = blockIdx.z;
  float acc[16];
  #pragma unroll
  for (int j = 0; j < 16; j++) acc[j] = 0.f;

  for (int ph = 0; ph < 2; ph++) {
    __syncthreads();
    for (int idx = tt; idx < 32 * 320; idx += 256) {
      int kh = idx / 320;
      int tl = idx - kh * 320;
      int gt = t0 - 32 + tl;
      float v = 0.f;
      if (gt >= 0 && gt < 1000) v = x[(b * 64 + ph * 32 + kh) * 1000 + gt];
      xs[idx] = v;
    }
    __syncthreads();
    for (int kh2 = 0; kh2 < 32; kh2++) {
      const float* xrow = &xs[kh2 * 320 + tt];
      const float* wrow = Wt + ((ph * 32 + kh2) * 65) * 128 + o0;
      #pragma unroll
      for (int u = 0; u < 65; u++) {
        float xv = xrow[u];
        const float* wp = wrow + u * 128;
        #pragma unroll
        for (int j = 0; j < 16; j++) acc[j] = fmaf(wp[j], xv, acc[j]);
      }
    }
  }
  int t = t0 + tt;
  if (t < 1000) {
    #pragma unroll
    for (int j = 0; j < 16; j++) {
      int o = o0 + j;
      float s2 = bn2g[o] * BN_S;
      float v = (acc[j] + biasEff[o]) * s2 + bn2b[o];
      z[(b * 128 + o) * 1000 + t] = eluf(v);
    }
  }
}

// ============================================================
// k_pool: windows of 50, stride 15, npos=64. mean -> x1, log(clip(var,ddof=1)) -> x2.
// Writes transposed: X[(s*16+b)*64 + p][o]. grid (64 p, 16 b), 128 threads (o).
// ============================================================
__global__ __launch_bounds__(128) void k_pool(const float* __restrict__ z, float* __restrict__ X) {
  int p = blockIdx.x, b = blockIdx.y, o = threadIdx.x;
  const float* zp = z + (b * 128 + o) * 1000 + p * 15;
  float s = 0.f, ss = 0.f;
  #pragma unroll
  for (int k = 0; k < 50; k++) { float v = zp[k]; s += v; ss = fmaf(v, v, ss); }
  float m = s * 0.02f;
  float var = (ss - s * m) * (1.f / 49.f);
  var = fminf(fmaxf(var, 1e-6f), 1e6f);
  X[(b * 64 + p) * 128 + o] = m;
  X[((16 + b) * 64 + p) * 128 + o] = logf(var);
}

// ============================================================
// k_ln: LayerNorm over d=128. One wave per row, 2 elems per lane.
// ============================================================
__global__ __launch_bounds__(64) void k_ln(const float* __restrict__ X, float* __restrict__ H,
                                           const float* __restrict__ g, const float* __restrict__ b) {
  int r = blockIdx.x, lane = threadIdx.x;
  float v0 = X[r * 128 + lane], v1 = X[r * 128 + 64 + lane];
  float s = v0 + v1;
  #pragma unroll
  for (int off = 32; off; off >>= 1) s += __shfl_xor(s, off);
  float m = s * (1.f / 128.f);
  float d0 = v0 - m, d1 = v1 - m;
  float q = d0 * d0 + d1 * d1;
  #pragma unroll
  for (int off = 32; off; off >>= 1) q += __shfl_xor(q, off);
  float rs = rsqrtf(q * (1.f / 128.f) + 1e-5f);
  H[r * 128 + lane]      = d0 * rs * g[lane] + b[lane];
  H[r * 128 + 64 + lane] = d1 * rs * g[64 + lane] + b[64 + lane];
}

// ============================================================
// k_gemm: C[2048][N] = act(A[2048][K] @ W[N][K]^T + bias) (+R). 64x64 tile,
// 256 threads, 4x4 micro-tile, BK=16. M=2048, N%64==0, K%16==0.
// act: 0 none, 1 gelu(exact erf).
// ============================================================
__global__ __launch_bounds__(256) void k_gemm(const float* __restrict__ A, const float* __restrict__ W,
                                              const float* __restrict__ bias, const float* __restrict__ R,
                                              float* __restrict__ C, int N, int K, int act) {
  __shared__ float As[16][68];
  __shared__ float Ws[16][68];
  int tid = threadIdx.x;
  int tx = tid & 15, ty = tid >> 4;
  int m0 = blockIdx.x * 64, n0 = blockIdx.y * 64;
  int lr = tid >> 2, lk = (tid & 3) * 4;
  float acc[4][4] = {};
  for (int k0 = 0; k0 < K; k0 += 16) {
    float4 av = *(const float4*)(A + (m0 + lr) * K + k0 + lk);
    As[lk + 0][lr] = av.x; As[lk + 1][lr] = av.y; As[lk + 2][lr] = av.z; As[lk + 3][lr] = av.w;
    float4 wv = *(const float4*)(W + (n0 + lr) * K + k0 + lk);
    Ws[lk + 0][lr] = wv.x; Ws[lk + 1][lr] = wv.y;
    Ws[lk + 2][lr] = wv.z; Ws[lk + 3][lr] = wv.w;
    __syncthreads();
    #pragma unroll
    for (int kk = 0; kk < 16; kk++) {
      float a[4], bv[4];
      #pragma unroll
      for (int i = 0; i < 4; i++) a[i] = As[kk][ty * 4 + i];
      #pragma unroll
      for (int j = 0; j < 4; j++) bv[j] = Ws[kk][tx * 4 + j];
      #pragma unroll
      for (int i = 0; i < 4; i++)
        #pragma unroll
        for (int j = 0; j < 4; j++)
          acc[i][j] = fmaf(a[i], bv[j], acc[i][j]);
    }
    __syncthreads();
  }
  #pragma unroll
  for (int i = 0; i < 4; i++) {
    int m = m0 + ty * 4 + i;
    #pragma unroll
    for (int j = 0; j < 4; j++) {
      int n = n0 + tx * 4 + j;
      float v = acc[i][j] + bias[n];
      if (act == 1) v = geluf(v);
      if (R) v += R[m * N + n];
      C[m * N + n] = v;
    }
  }
}

// ============================================================
// k_attn: per (batch-row bb, head h) attention. n=64 tokens, dh=16, scale 0.25.
// One wave; lane = query row. grid (32, 8).
// ============================================================
__global__ __launch_bounds__(64) void k_attn(const float* __restrict__ Q, const float* __restrict__ K,
                                             const float* __restrict__ V, float* __restrict__ AO) {
  __shared__ float Ks[1024], Vs[1024], Ss[64 * 65];
  int bb = blockIdx.x, h = blockIdx.y, lane = threadIdx.x;
  int base = (bb * 64) * 128 + h * 16;
  for (int idx = lane; idx < 1024; idx += 64) {
    int n = idx >> 4, j = idx & 15;
    Ks[idx] = K[base + n * 128 + j];
    Vs[idx] = V[base + n * 128 + j];
  }
  __syncthreads();
  float q[16];
  #pragma unroll
  for (int j = 0; j < 16; j++) q[j] = Q[base + lane * 128 + j];
  float mx = -1e30f;
  for (int k = 0; k < 64; k++) {
    float s = 0.f;
    #pragma unroll
    for (int j = 0; j < 16; j++) s = fmaf(q[j], Ks[k * 16 + j], s);
    s *= 0.25f;
    Ss[lane * 65 + k] = s;
    mx = fmaxf(mx, s);
  }
  float l = 0.f, o[16];
  #pragma unroll
  for (int j = 0; j < 16; j++) o[j] = 0.f;
  for (int k = 0; k < 64; k++) {
    float p = __expf(Ss[lane * 65 + k] - mx);
    l += p;
    #pragma unroll
    for (int j = 0; j < 16; j++) o[j] = fmaf(p, Vs[k * 16 + j], o[j]);
  }
  float inv = 1.f / l;
  #pragma unroll
  for (int j = 0; j < 16; j++) AO[base + lane * 128 + j] = o[j] * inv;
}

// ============================================================
// k_head: 2-tap conv over streams + bn3 + elu, then classifier. grid 16 (b).
// ============================================================
__global__ __launch_bounds__(256) void k_head(const float* __restrict__ X, const float* __restrict__ ew,
                                              const float* __restrict__ eb, const float* __restrict__ g3,
                                              const float* __restrict__ b3, const float* __restrict__ cw,
                                              const float* __restrict__ cb, float* __restrict__ out) {
  __shared__ float gbuf[8192];
  __shared__ float red[256];
  int b = blockIdx.x, tid = threadIdx.x;
  for (int idx = tid; idx < 8192; idx += 256) {
    int oc = idx >> 7, w = idx & 127;
    float a = 0.f;
    #pragma unroll 8
    for (int ic = 0; ic < 64; ic++) {
      a = fmaf(ew[(oc * 64 + ic) * 2 + 0], X[(b * 64 + ic) * 128 + w], a);
      a = fmaf(ew[(oc * 64 + ic) * 2 + 1], X[((16 + b) * 64 + ic) * 128 + w], a);
    }
    a += eb[oc];
    float v = a * (g3[oc] * BN_S) + b3[oc];
    gbuf[idx] = eluf(v);
  }
  __syncthreads();
  for (int c = 0; c < 4; c++) {
    float p = 0.f;
    for (int idx = tid; idx < 8192; idx += 256) p = fmaf(gbuf[idx], cw[c * 8192 + idx], p);
    red[tid] = p;
    __syncthreads();
    for (int s = 128; s > 0; s >>= 1) {
      if (tid < s) red[tid] += red[tid + s];
      __syncthreads();
    }
    if (tid == 0) out[b * 4 + c] = red[0] + cb[c];
    __syncthreads();
  }
}

// ============================================================
extern "C" void kernel_launch(void* const* d_in, const int* in_sizes, int n_in,
                              void* d_out, int out_size, void* d_ws, size_t ws_size,
                              hipStream_t stream) {
  const float* x    = (const float*)d_in[0];
  const float* tw1  = (const float*)d_in[1];  const float* tb1 = (const float*)d_in[2];
  const float* tw2  = (const float*)d_in[3];  const float* tb2 = (const float*)d_in[4];
  const float* tw3  = (const float*)d_in[5];  const float* tb3 = (const float*)d_in[6];
  const float* tw4  = (const float*)d_in[7];  const float* tb4 = (const float*)d_in[8];
  const float* bn1g = (const float*)d_in[9];  const float* bn1b = (const float*)d_in[10];
  const float* sw   = (const float*)d_in[11]; const float* sb   = (const float*)d_in[12];
  const float* bn2g = (const float*)d_in[13]; const float* bn2b = (const float*)d_in[14];
  const float* ln1g = (const float*)d_in[15]; const float* ln1b = (const float*)d_in[16];
  const float* ln2g = (const float*)d_in[17]; const float* ln2b = (const float*)d_in[18];
  const float* wq   = (const float*)d_in[19]; const float* bq   = (const float*)d_in[20];
  const float* wk   = (const float*)d_in[21]; const float* bk   = (const float*)d_in[22];
  const float* wv   = (const float*)d_in[23]; const float* bv   = (const float*)d_in[24];
  const float* wo   = (const float*)d_in[25]; const float* bo   = (const float*)d_in[26];
  const float* f1w  = (const float*)d_in[27]; const float* f1b  = (const float*)d_in[28];
  const float* f2w  = (const float*)d_in[29]; const float* f2b  = (const float*)d_in[30];
  const float* ew   = (const float*)d_in[31]; const float* eb   = (const float*)d_in[32];
  const float* g3   = (const float*)d_in[33]; const float* b3   = (const float*)d_in[34];
  const float* cw   = (const float*)d_in[35]; const float* cb   = (const float*)d_in[36];

  // workspace layout (fp32 elements); total 5,210,496 floats = 20.9 MB
  float* ws      = (float*)d_ws;
  float* tws1    = ws;               // 8320
  float* c1      = ws + 8320;        // 128
  float* biasEff = ws + 8448;        // 128
  float* Wt      = ws + 8576;        // 532480  [kh][u][o]
  float* z       = ws + 541056;      // 2048000 [b][o][t]
  float* X       = ws + 2589056;     // 262144  [2048][128]
  float* H       = ws + 2851200;     // 262144
  float* Qb      = ws + 3113344;     // 262144
  float* Kb      = ws + 3375488;     // 262144
  float* Vb      = ws + 3637632;     // 262144
  float* AO      = ws + 3899776;     // 262144
  float* F1      = ws + 4161920;     // 1048576 [2048][512]

  k_tws1<<<33, 256, 0, stream>>>(tw1, tw2, tw3, tw4, tb1, tb2, tb3, tb4, bn1g, bn1b, tws1, c1);
  k_weff<<<128, 256, 0, stream>>>(sw, sb, tws1, c1, Wt, biasEff);
  k_conv<<<dim3(4, 8, 16), 256, 0, stream>>>(x, Wt, biasEff, bn2g, bn2b, z);
  k_pool<<<dim3(64, 16), 128, 0, stream>>>(z, X);

  for (int l = 0; l < 4; l++) {
    k_ln<<<2048, 64, 0, stream>>>(X, H, ln1g + l * 128, ln1b + l * 128);
    k_gemm<<<dim3(32, 2), 256, 0, stream>>>(H, wq + l * 16384, bq + l * 128, nullptr, Qb, 128, 128, 0);
    k_gemm<<<dim3(32, 2), 256, 0, stream>>>(H, wk + l * 16384, bk + l * 128, nullptr, Kb, 128, 128, 0);
    k_gemm<<<dim3(32, 2), 256, 0, stream>>>(H, wv + l * 16384, bv + l * 128, nullptr, Vb, 128, 128, 0);
    k_attn<<<dim3(32, 8), 64, 0, stream>>>(Qb, Kb, Vb, AO);
    k_gemm<<<dim3(32, 2), 256, 0, stream>>>(AO, wo + l * 16384, bo + l * 128, X, X, 128, 128, 0);
    k_ln<<<2048, 64, 0, stream>>>(X, H, ln2g + l * 128, ln2b + l * 128);
    k_gemm<<<dim3(32, 8), 256, 0, stream>>>(H, f1w + l * 65536, f1b + l * 512, nullptr, F1, 512, 128, 1);
    k_gemm<<<dim3(32, 2), 256, 0, stream>>>(F1, f2w + l * 65536, f2b + l * 128, X, X, 128, 512, 0);
  }

  k_head<<<16, 256, 0, stream>>>(X, ew, eb, g3, b3, cw, cb, (float*)d_out);
}

// Round 3
// 959.142 us; speedup vs baseline: 1.0635x; 1.0635x over previous
//
#include <hip/hip_runtime.h>
#include <math.h>

__device__ __forceinline__ float eluf(float v) { return v > 0.f ? v : expm1f(v); }
__device__ __forceinline__ float geluf(float v) {
  return 0.5f * v * (1.f + erff(v * 0.70710678118654752f));
}

#define BN_S 0.99999500003749969f   /* 1/sqrt(1+1e-5) */

// ============================================================
// k_tws1: tws1[i][u] = s1[i] * tw_g[i%32][u-32+P_g]  (0 outside window)
//         c1[i]     = s1[i]*tb[i] + bn1_b[i]
// ============================================================
__global__ void k_tws1(const float* tw1, const float* tw2, const float* tw3, const float* tw4,
                       const float* tb1, const float* tb2, const float* tb3, const float* tb4,
                       const float* bn1g, const float* bn1b,
                       float* tws1, float* c1) {
  int idx = blockIdx.x * 256 + threadIdx.x;
  if (idx < 8320) {
    int i = idx / 65, u = idx - i * 65;
    int g = i >> 5, il = i & 31;
    const float* tws[4] = {tw1, tw2, tw3, tw4};
    const int P[4] = {7, 12, 25, 32};
    int c = u - 32;
    float s1 = bn1g[i] * BN_S;
    float val = 0.f;
    int p = P[g];
    if (c >= -p && c <= p) val = s1 * tws[g][il * (2 * p + 1) + (c + p)];
    tws1[idx] = val;
  } else if (idx < 8448) {
    int i = idx - 8320;
    int g = i >> 5, il = i & 31;
    const float* tbs[4] = {tb1, tb2, tb3, tb4};
    float s1 = bn1g[i] * BN_S;
    c1[i] = s1 * tbs[g][il] + bn1b[i];
  }
}

// ============================================================
// k_weff: Wt[(kh*65+u)*128 + o] = sum_i sw[o,i,kh] * tws1[i][u]
//         biasEff[o] = sb[o] + sum_{i,kh} sw[o,i,kh]*c1[i]
// one block per o; sw row staged in LDS (kills the stride-64 global reads).
// ============================================================
__global__ __launch_bounds__(256) void k_weff(const float* __restrict__ sw, const float* __restrict__ sb,
                                              const float* __restrict__ tws1, const float* __restrict__ c1,
                                              float* __restrict__ Wt, float* __restrict__ biasEff) {
  __shared__ float swl[8192];   // 32 KB: sw[o][i][kh]
  __shared__ float red[256];
  int o = blockIdx.x, tid = threadIdx.x;
  const float* swo = sw + o * 8192;
  for (int j = tid; j < 8192; j += 256) swl[j] = swo[j];
  __syncthreads();
  for (int idx = tid; idx < 4160; idx += 256) {
    int kh = idx / 65, u = idx - kh * 65;
    float a = 0.f;
    #pragma unroll 4
    for (int i = 0; i < 128; i++)
      a = fmaf(swl[i * 64 + kh], tws1[i * 65 + u], a);
    Wt[idx * 128 + o] = a;
  }
  float pa = 0.f;
  for (int j = tid; j < 8192; j += 256)
    pa = fmaf(swl[j], c1[j >> 6], pa);
  red[tid] = pa;
  __syncthreads();
  for (int s = 128; s > 0; s >>= 1) {
    if (tid < s) red[tid] += red[tid + s];
    __syncthreads();
  }
  if (tid == 0) biasEff[o] = red[0] + sb[o];
}

// ============================================================
// k_conv: fused (temporal+spatial) conv + bn2 + elu.
// Block: 256 threads, t-tile 512 (2 t/thread), o-tile 8 (all per-thread).
// Grid (2 t-tiles, 16 o-tiles, 16 b) = 512 blocks = 2 blocks/CU.
// x staged in LDS per 8-kh phase, then copied to a 68-wide REGISTER window
// per kh; weights are wave-uniform global loads (scalarizable s_load).
// Inner loop: 16 FMAs per (kh,u) with zero per-iteration LDS dependency.
// ============================================================
__global__ __launch_bounds__(256) void k_conv(const float* __restrict__ x,
                                              const float* __restrict__ Wt,
                                              const float* __restrict__ biasEff,
                                              const float* __restrict__ bn2g, const float* __restrict__ bn2b,
                                              float* __restrict__ z) {
  __shared__ float xs[8][584];   // 18.7 KB; row = kh, col j -> x[t0-32+j], j in [0,577)
  const int tid = threadIdx.x;
  const int t0 = blockIdx.x * 512;
  const int o0 = blockIdx.y * 8;
  const int b  = blockIdx.z;
  float acc0[8], acc1[8];
  #pragma unroll
  for (int j = 0; j < 8; j++) { acc0[j] = 0.f; acc1[j] = 0.f; }
  const int tbase = 2 * tid;

  #pragma unroll 1
  for (int ph = 0; ph < 8; ph++) {
    __syncthreads();
    for (int idx = tid; idx < 8 * 577; idx += 256) {
      int kh = idx / 577, j = idx - kh * 577;
      int gt = t0 - 32 + j;
      float v = 0.f;
      if (gt >= 0 && gt < 1000) v = x[(b * 64 + ph * 8 + kh) * 1000 + gt];
      xs[kh][j] = v;
    }
    __syncthreads();
    #pragma unroll 1
    for (int kh = 0; kh < 8; kh++) {
      float xw[68];
      #pragma unroll
      for (int c = 0; c < 34; c++) {          // b64 LDS reads, 8B-aligned
        float2 v = *(const float2*)&xs[kh][tbase + 2 * c];
        xw[2 * c] = v.x; xw[2 * c + 1] = v.y;
      }
      const float* wrow = Wt + ((ph * 8 + kh) * 65) * 128 + o0;   // wave-uniform
      #pragma unroll
      for (int u = 0; u < 65; u++) {
        const float* wp = wrow + u * 128;
        float xa = xw[u], xb = xw[u + 1];
        #pragma unroll
        for (int j = 0; j < 8; j++) {
          float w = wp[j];
          acc0[j] = fmaf(w, xa, acc0[j]);
          acc1[j] = fmaf(w, xb, acc1[j]);
        }
      }
    }
  }
  int t = t0 + tbase;   // even
  if (t < 1000) {
    #pragma unroll
    for (int j = 0; j < 8; j++) {
      int o = o0 + j;
      float s2 = bn2g[o] * BN_S;
      float be = biasEff[o], bb = bn2b[o];
      float2 v;
      v.x = eluf((acc0[j] + be) * s2 + bb);
      v.y = eluf((acc1[j] + be) * s2 + bb);
      *(float2*)&z[(b * 128 + o) * 1000 + t] = v;
    }
  }
}

// ============================================================
// k_pool: windows of 50, stride 15, npos=64. mean -> x1, log(var,ddof=1) -> x2.
// ============================================================
__global__ __launch_bounds__(128) void k_pool(const float* __restrict__ z, float* __restrict__ X) {
  int p = blockIdx.x, b = blockIdx.y, o = threadIdx.x;
  const float* zp = z + (b * 128 + o) * 1000 + p * 15;
  float s = 0.f, ss = 0.f;
  #pragma unroll
  for (int k = 0; k < 50; k++) { float v = zp[k]; s += v; ss = fmaf(v, v, ss); }
  float m = s * 0.02f;
  float var = (ss - s * m) * (1.f / 49.f);
  var = fminf(fmaxf(var, 1e-6f), 1e6f);
  X[(b * 64 + p) * 128 + o] = m;
  X[((16 + b) * 64 + p) * 128 + o] = logf(var);
}

// ============================================================
// k_ln: LayerNorm over d=128. One wave per row.
// ============================================================
__global__ __launch_bounds__(64) void k_ln(const float* __restrict__ X, float* __restrict__ H,
                                           const float* __restrict__ g, const float* __restrict__ b) {
  int r = blockIdx.x, lane = threadIdx.x;
  float v0 = X[r * 128 + lane], v1 = X[r * 128 + 64 + lane];
  float s = v0 + v1;
  #pragma unroll
  for (int off = 32; off; off >>= 1) s += __shfl_xor(s, off);
  float m = s * (1.f / 128.f);
  float d0 = v0 - m, d1 = v1 - m;
  float q = d0 * d0 + d1 * d1;
  #pragma unroll
  for (int off = 32; off; off >>= 1) q += __shfl_xor(q, off);
  float rs = rsqrtf(q * (1.f / 128.f) + 1e-5f);
  H[r * 128 + lane]      = d0 * rs * g[lane] + b[lane];
  H[r * 128 + 64 + lane] = d1 * rs * g[64 + lane] + b[64 + lane];
}

// ============================================================
// k_gemm: C = act(A[2048,K] @ W[N,K]^T + bias) (+R). 64x64 tile, 4x4 micro.
// blockIdx.z selects among up to 3 (W,bias,C) triples (QKV batching).
// ============================================================
__global__ __launch_bounds__(256) void k_gemm(const float* __restrict__ A,
                                              const float* __restrict__ W0, const float* __restrict__ W1, const float* __restrict__ W2,
                                              const float* __restrict__ b0, const float* __restrict__ b1, const float* __restrict__ b2,
                                              float* __restrict__ C0, float* __restrict__ C1, float* __restrict__ C2,
                                              const float* __restrict__ R, int N, int K, int act) {
  const float* W = (blockIdx.z == 0) ? W0 : (blockIdx.z == 1) ? W1 : W2;
  const float* bias = (blockIdx.z == 0) ? b0 : (blockIdx.z == 1) ? b1 : b2;
  float* C = (blockIdx.z == 0) ? C0 : (blockIdx.z == 1) ? C1 : C2;
  __shared__ float As[16][68];
  __shared__ float Ws[16][68];
  int tid = threadIdx.x;
  int tx = tid & 15, ty = tid >> 4;
  int m0 = blockIdx.x * 64, n0 = blockIdx.y * 64;
  int lr = tid >> 2, lk = (tid & 3) * 4;
  float acc[4][4] = {};
  for (int k0 = 0; k0 < K; k0 += 16) {
    float4 av = *(const float4*)(A + (m0 + lr) * K + k0 + lk);
    As[lk + 0][lr] = av.x; As[lk + 1][lr] = av.y; As[lk + 2][lr] = av.z; As[lk + 3][lr] = av.w;
    float4 wv = *(const float4*)(W + (n0 + lr) * K + k0 + lk);
    Ws[lk + 0][lr] = wv.x; Ws[lk + 1][lr] = wv.y;
    Ws[lk + 2][lr] = wv.z; Ws[lk + 3][lr] = wv.w;
    __syncthreads();
    #pragma unroll
    for (int kk = 0; kk < 16; kk++) {
      float a[4], bv[4];
      #pragma unroll
      for (int i = 0; i < 4; i++) a[i] = As[kk][ty * 4 + i];
      #pragma unroll
      for (int j = 0; j < 4; j++) bv[j] = Ws[kk][tx * 4 + j];
      #pragma unroll
      for (int i = 0; i < 4; i++)
        #pragma unroll
        for (int j = 0; j < 4; j++)
          acc[i][j] = fmaf(a[i], bv[j], acc[i][j]);
    }
    __syncthreads();
  }
  #pragma unroll
  for (int i = 0; i < 4; i++) {
    int m = m0 + ty * 4 + i;
    #pragma unroll
    for (int j = 0; j < 4; j++) {
      int n = n0 + tx * 4 + j;
      float v = acc[i][j] + bias[n];
      if (act == 1) v = geluf(v);
      if (R) v += R[m * N + n];
      C[m * N + n] = v;
    }
  }
}

// ============================================================
// k_attn: per (batch-row bb, head h). n=64, dh=16, scale 0.25. grid (32,8).
// ============================================================
__global__ __launch_bounds__(64) void k_attn(const float* __restrict__ Q, const float* __restrict__ K,
                                             const float* __restrict__ V, float* __restrict__ AO) {
  __shared__ float Ks[1024], Vs[1024], Ss[64 * 65];
  int bb = blockIdx.x, h = blockIdx.y, lane = threadIdx.x;
  int base = (bb * 64) * 128 + h * 16;
  for (int idx = lane; idx < 1024; idx += 64) {
    int n = idx >> 4, j = idx & 15;
    Ks[idx] = K[base + n * 128 + j];
    Vs[idx] = V[base + n * 128 + j];
  }
  __syncthreads();
  float q[16];
  #pragma unroll
  for (int j = 0; j < 16; j++) q[j] = Q[base + lane * 128 + j];
  float mx = -1e30f;
  for (int k = 0; k < 64; k++) {
    float s = 0.f;
    #pragma unroll
    for (int j = 0; j < 16; j++) s = fmaf(q[j], Ks[k * 16 + j], s);
    s *= 0.25f;
    Ss[lane * 65 + k] = s;
    mx = fmaxf(mx, s);
  }
  float l = 0.f, o[16];
  #pragma unroll
  for (int j = 0; j < 16; j++) o[j] = 0.f;
  for (int k = 0; k < 64; k++) {
    float p = __expf(Ss[lane * 65 + k] - mx);
    l += p;
    #pragma unroll
    for (int j = 0; j < 16; j++) o[j] = fmaf(p, Vs[k * 16 + j], o[j]);
  }
  float inv = 1.f / l;
  #pragma unroll
  for (int j = 0; j < 16; j++) AO[base + lane * 128 + j] = o[j] * inv;
}

// ============================================================
// k_head: 2-tap conv + bn3 + elu, then classifier. grid 16 (b).
// ============================================================
__global__ __launch_bounds__(256) void k_head(const float* __restrict__ X, const float* __restrict__ ew,
                                              const float* __restrict__ eb, const float* __restrict__ g3,
                                              const float* __restrict__ b3, const float* __restrict__ cw,
                                              const float* __restrict__ cb, float* __restrict__ out) {
  __shared__ float gbuf[8192];
  __shared__ float red[256];
  int b = blockIdx.x, tid = threadIdx.x;
  for (int idx = tid; idx < 8192; idx += 256) {
    int oc = idx >> 7, w = idx & 127;
    float a = 0.f;
    #pragma unroll 8
    for (int ic = 0; ic < 64; ic++) {
      a = fmaf(ew[(oc * 64 + ic) * 2 + 0], X[(b * 64 + ic) * 128 + w], a);
      a = fmaf(ew[(oc * 64 + ic) * 2 + 1], X[((16 + b) * 64 + ic) * 128 + w], a);
    }
    a += eb[oc];
    float v = a * (g3[oc] * BN_S) + b3[oc];
    gbuf[idx] = eluf(v);
  }
  __syncthreads();
  for (int c = 0; c < 4; c++) {
    float p = 0.f;
    for (int idx = tid; idx < 8192; idx += 256) p = fmaf(gbuf[idx], cw[c * 8192 + idx], p);
    red[tid] = p;
    __syncthreads();
    for (int s = 128; s > 0; s >>= 1) {
      if (tid < s) red[tid] += red[tid + s];
      __syncthreads();
    }
    if (tid == 0) out[b * 4 + c] = red[0] + cb[c];
    __syncthreads();
  }
}

// ============================================================
extern "C" void kernel_launch(void* const* d_in, const int* in_sizes, int n_in,
                              void* d_out, int out_size, void* d_ws, size_t ws_size,
                              hipStream_t stream) {
  const float* x    = (const float*)d_in[0];
  const float* tw1  = (const float*)d_in[1];  const float* tb1 = (const float*)d_in[2];
  const float* tw2  = (const float*)d_in[3];  const float* tb2 = (const float*)d_in[4];
  const float* tw3  = (const float*)d_in[5];  const float* tb3 = (const float*)d_in[6];
  const float* tw4  = (const float*)d_in[7];  const float* tb4 = (const float*)d_in[8];
  const float* bn1g = (const float*)d_in[9];  const float* bn1b = (const float*)d_in[10];
  const float* sw   = (const float*)d_in[11]; const float* sb   = (const float*)d_in[12];
  const float* bn2g = (const float*)d_in[13]; const float* bn2b = (const float*)d_in[14];
  const float* ln1g = (const float*)d_in[15]; const float* ln1b = (const float*)d_in[16];
  const float* ln2g = (const float*)d_in[17]; const float* ln2b = (const float*)d_in[18];
  const float* wq   = (const float*)d_in[19]; const float* bq   = (const float*)d_in[20];
  const float* wk   = (const float*)d_in[21]; const float* bk   = (const float*)d_in[22];
  const float* wv   = (const float*)d_in[23]; const float* bv   = (const float*)d_in[24];
  const float* wo   = (const float*)d_in[25]; const float* bo   = (const float*)d_in[26];
  const float* f1w  = (const float*)d_in[27]; const float* f1b  = (const float*)d_in[28];
  const float* f2w  = (const float*)d_in[29]; const float* f2b  = (const float*)d_in[30];
  const float* ew   = (const float*)d_in[31]; const float* eb   = (const float*)d_in[32];
  const float* g3   = (const float*)d_in[33]; const float* b3   = (const float*)d_in[34];
  const float* cw   = (const float*)d_in[35]; const float* cb   = (const float*)d_in[36];

  float* ws      = (float*)d_ws;
  float* tws1    = ws;               // 8320
  float* c1      = ws + 8320;        // 128
  float* biasEff = ws + 8448;        // 128
  float* Wt      = ws + 8576;        // 532480  [kh][u][o]
  float* z       = ws + 541056;      // 2048000 [b][o][t]
  float* X       = ws + 2589056;     // 262144  [2048][128]
  float* H       = ws + 2851200;     // 262144
  float* Qb      = ws + 3113344;     // 262144
  float* Kb      = ws + 3375488;     // 262144
  float* Vb      = ws + 3637632;     // 262144
  float* AO      = ws + 3899776;     // 262144
  float* F1      = ws + 4161920;     // 1048576 [2048][512]

  k_tws1<<<33, 256, 0, stream>>>(tw1, tw2, tw3, tw4, tb1, tb2, tb3, tb4, bn1g, bn1b, tws1, c1);
  k_weff<<<128, 256, 0, stream>>>(sw, sb, tws1, c1, Wt, biasEff);
  k_conv<<<dim3(2, 16, 16), 256, 0, stream>>>(x, Wt, biasEff, bn2g, bn2b, z);
  k_pool<<<dim3(64, 16), 128, 0, stream>>>(z, X);

  for (int l = 0; l < 4; l++) {
    const float* WQ = wq + l * 16384; const float* WK = wk + l * 16384; const float* WV = wv + l * 16384;
    k_ln<<<2048, 64, 0, stream>>>(X, H, ln1g + l * 128, ln1b + l * 128);
    k_gemm<<<dim3(32, 2, 3), 256, 0, stream>>>(H, WQ, WK, WV,
                                               bq + l * 128, bk + l * 128, bv + l * 128,
                                               Qb, Kb, Vb, nullptr, 128, 128, 0);
    k_attn<<<dim3(32, 8), 64, 0, stream>>>(Qb, Kb, Vb, AO);
    k_gemm<<<dim3(32, 2, 1), 256, 0, stream>>>(AO, wo + l * 16384, nullptr, nullptr,
                                               bo + l * 128, nullptr, nullptr,
                                               X, nullptr, nullptr, X, 128, 128, 0);
    k_ln<<<2048, 64, 0, stream>>>(X, H, ln2g + l * 128, ln2b + l * 128);
    k_gemm<<<dim3(32, 8, 1), 256, 0, stream>>>(H, f1w + l * 65536, nullptr, nullptr,
                                               f1b + l * 512, nullptr, nullptr,
                                               F1, nullptr, nullptr, nullptr, 512, 128, 1);
    k_gemm<<<dim3(32, 2, 1), 256, 0, stream>>>(F1, f2w + l * 65536, nullptr, nullptr,
                                               f2b + l * 128, nullptr, nullptr,
                                               X, nullptr, nullptr, X, 128, 512, 0);
  }

  k_head<<<16, 256, 0, stream>>>(X, ew, eb, g3, b3, cw, cb, (float*)d_out);
}

// Round 4
// 725.972 us; speedup vs baseline: 1.4051x; 1.3212x over previous
//
#include <hip/hip_runtime.h>
#include <math.h>

typedef unsigned short u16;
typedef __attribute__((ext_vector_type(8))) short frag8;   // 8 bf16 = 4 VGPR
typedef __attribute__((ext_vector_type(4))) float f32x4;   // MFMA acc

__device__ __forceinline__ float eluf(float v) { return v > 0.f ? v : expm1f(v); }
__device__ __forceinline__ float geluf(float v) {
  return 0.5f * v * (1.f + erff(v * 0.70710678118654752f));
}
__device__ __forceinline__ u16 f2bf(float f) {
  union { float f; unsigned int i; } v; v.f = f;
  return (u16)((v.i + 0x7fffu + ((v.i >> 16) & 1u)) >> 16);
}

#define BN_S 0.99999500003749969f   /* 1/sqrt(1+1e-5) */

// ============================================================
// k_tws1: tws1[i][u] = s1[i] * tw_g[i%32][u-32+P_g]  (0 outside window)
//         c1[i]     = s1[i]*tb[i] + bn1_b[i]
// ============================================================
__global__ void k_tws1(const float* tw1, const float* tw2, const float* tw3, const float* tw4,
                       const float* tb1, const float* tb2, const float* tb3, const float* tb4,
                       const float* bn1g, const float* bn1b,
                       float* tws1, float* c1) {
  int idx = blockIdx.x * 256 + threadIdx.x;
  if (idx < 8320) {
    int i = idx / 65, u = idx - i * 65;
    int g = i >> 5, il = i & 31;
    const float* tws[4] = {tw1, tw2, tw3, tw4};
    const int P[4] = {7, 12, 25, 32};
    int c = u - 32;
    float s1 = bn1g[i] * BN_S;
    float val = 0.f;
    int p = P[g];
    if (c >= -p && c <= p) val = s1 * tws[g][il * (2 * p + 1) + (c + p)];
    tws1[idx] = val;
  } else if (idx < 8448) {
    int i = idx - 8320;
    int g = i >> 5, il = i & 31;
    const float* tbs[4] = {tb1, tb2, tb3, tb4};
    float s1 = bn1g[i] * BN_S;
    c1[i] = s1 * tbs[g][il] + bn1b[i];
  }
}

// ============================================================
// k_weff: Wb[u][o][kh] (bf16) = sum_i sw[o,i,kh] * tws1[i][u]
//         biasEff[o] = sb[o] + sum_{i,kh} sw[o,i,kh]*c1[i]
// one block per o; sw row staged in LDS.
// ============================================================
__global__ __launch_bounds__(256) void k_weff(const float* __restrict__ sw, const float* __restrict__ sb,
                                              const float* __restrict__ tws1, const float* __restrict__ c1,
                                              u16* __restrict__ Wb, float* __restrict__ biasEff) {
  __shared__ float swl[8192];   // 32 KB: sw[o][i][kh]
  __shared__ float red[256];
  int o = blockIdx.x, tid = threadIdx.x;
  const float* swo = sw + o * 8192;
  for (int j = tid; j < 8192; j += 256) swl[j] = swo[j];
  __syncthreads();
  for (int idx = tid; idx < 4160; idx += 256) {
    int kh = idx / 65, u = idx - kh * 65;
    float a = 0.f;
    #pragma unroll 4
    for (int i = 0; i < 128; i++)
      a = fmaf(swl[i * 64 + kh], tws1[i * 65 + u], a);
    Wb[(u * 128 + o) * 64 + kh] = f2bf(a);
  }
  float pa = 0.f;
  for (int j = tid; j < 8192; j += 256)
    pa = fmaf(swl[j], c1[j >> 6], pa);
  red[tid] = pa;
  __syncthreads();
  for (int s = 128; s > 0; s >>= 1) {
    if (tid < s) red[tid] += red[tid + s];
    __syncthreads();
  }
  if (tid == 0) biasEff[o] = red[0] + sb[o];
}

// ============================================================
// k_conv (MFMA): z[b][o][t] = elu(bn2(conv)). Per u in [0,65):
//   C[t][o] += X_u[t][kh=0..63] * W_u[kh][o]   (K=64, 2 chunks of 32)
// A-frag: xs[t][kh] bf16 in LDS (row stride 88 -> 16B aligned, conflict-free
// b128). B-frag: Wb[u][o][kh] bf16 global (coalesced 16B, L2-resident).
// Block: 4 waves, tile 64t x 64o; wave tile 32t x 32o (2x2 16x16 C-tiles).
// Grid (16 t, 2 o, 16 b) = 512 blocks.
// ============================================================
__global__ __launch_bounds__(256) void k_conv(const float* __restrict__ x,
                                              const u16* __restrict__ Wb,
                                              const float* __restrict__ biasEff,
                                              const float* __restrict__ bn2g, const float* __restrict__ bn2b,
                                              float* __restrict__ z) {
  __shared__ u16 xs[128 * 88];   // 22.5 KB; row tt -> t0-32+tt, col kh
  const int tid = threadIdx.x;
  const int t0 = blockIdx.x * 64;
  const int o0 = blockIdx.y * 64;
  const int b  = blockIdx.z;

  // stage x[b][kh][t0-32 .. t0+95] -> xs[tt][kh] (bf16), coalesced float4 reads
  #pragma unroll
  for (int i = 0; i < 8; i++) {
    int pos = tid + i * 256;          // 2048 float4 slots = 64 kh x 32 slots
    int kh = pos >> 5;
    int tt = (pos & 31) * 4;
    int gt = t0 - 32 + tt;
    const float* xp = x + (b * 64 + kh) * 1000;
    float v[4];
    if (gt >= 0 && gt + 3 < 1000) {
      float4 f = *(const float4*)(xp + gt);
      v[0] = f.x; v[1] = f.y; v[2] = f.z; v[3] = f.w;
    } else {
      #pragma unroll
      for (int e = 0; e < 4; e++) { int g2 = gt + e; v[e] = (g2 >= 0 && g2 < 1000) ? xp[g2] : 0.f; }
    }
    #pragma unroll
    for (int e = 0; e < 4; e++) xs[(tt + e) * 88 + kh] = f2bf(v[e]);
  }
  __syncthreads();

  const int lane = tid & 63, wave = tid >> 6;
  const int wt = (wave & 1) * 32;     // wave t-offset within block tile
  const int wo = (wave >> 1) * 32;    // wave o-offset
  const int m = lane & 15, q = lane >> 4;

  f32x4 acc[2][2];                    // [t-sub][o-sub]
  #pragma unroll
  for (int i = 0; i < 2; i++)
    #pragma unroll
    for (int j = 0; j < 2; j++) acc[i][j] = (f32x4){0.f, 0.f, 0.f, 0.f};

  #pragma unroll 2
  for (int u = 0; u < 65; u++) {
    frag8 A[2][2], B[2][2];
    #pragma unroll
    for (int tp = 0; tp < 2; tp++)
      #pragma unroll
      for (int kc = 0; kc < 2; kc++)
        A[tp][kc] = *(const frag8*)&xs[(wt + tp * 16 + m + u) * 88 + kc * 32 + q * 8];
    #pragma unroll
    for (int op = 0; op < 2; op++)
      #pragma unroll
      for (int kc = 0; kc < 2; kc++)
        B[op][kc] = *(const frag8*)(Wb + ((u * 128) + o0 + wo + op * 16 + m) * 64 + kc * 32 + q * 8);
    #pragma unroll
    for (int tp = 0; tp < 2; tp++)
      #pragma unroll
      for (int op = 0; op < 2; op++) {
        acc[tp][op] = __builtin_amdgcn_mfma_f32_16x16x32_bf16(A[tp][0], B[op][0], acc[tp][op], 0, 0, 0);
        acc[tp][op] = __builtin_amdgcn_mfma_f32_16x16x32_bf16(A[tp][1], B[op][1], acc[tp][op], 0, 0, 0);
      }
  }

  // epilogue: C row = t = q*4+r, col = o = m  [m89 layout]
  #pragma unroll
  for (int op = 0; op < 2; op++) {
    int o = o0 + wo + op * 16 + m;
    float s2 = bn2g[o] * BN_S;
    float be = biasEff[o], b2 = bn2b[o];
    #pragma unroll
    for (int tp = 0; tp < 2; tp++) {
      #pragma unroll
      for (int r = 0; r < 4; r++) {
        int t = t0 + wt + tp * 16 + q * 4 + r;
        if (t < 1000)
          z[(b * 128 + o) * 1000 + t] = eluf((acc[tp][op][r] + be) * s2 + b2);
      }
    }
  }
}

// ============================================================
// k_pool: windows of 50, stride 15, npos=64. mean -> x1, log(var,ddof=1) -> x2.
// ============================================================
__global__ __launch_bounds__(128) void k_pool(const float* __restrict__ z, float* __restrict__ X) {
  int p = blockIdx.x, b = blockIdx.y, o = threadIdx.x;
  const float* zp = z + (b * 128 + o) * 1000 + p * 15;
  float s = 0.f, ss = 0.f;
  #pragma unroll
  for (int k = 0; k < 50; k++) { float v = zp[k]; s += v; ss = fmaf(v, v, ss); }
  float m = s * 0.02f;
  float var = (ss - s * m) * (1.f / 49.f);
  var = fminf(fmaxf(var, 1e-6f), 1e6f);
  X[(b * 64 + p) * 128 + o] = m;
  X[((16 + b) * 64 + p) * 128 + o] = logf(var);
}

// ============================================================
// k_ln: LayerNorm over d=128. 4 rows/block (one wave each).
// ============================================================
__global__ __launch_bounds__(256) void k_ln(const float* __restrict__ X, float* __restrict__ H,
                                            const float* __restrict__ g, const float* __restrict__ b) {
  int lane = threadIdx.x & 63;
  int r = blockIdx.x * 4 + (threadIdx.x >> 6);
  float v0 = X[r * 128 + lane], v1 = X[r * 128 + 64 + lane];
  float s = v0 + v1;
  #pragma unroll
  for (int off = 32; off; off >>= 1) s += __shfl_xor(s, off);
  float m = s * (1.f / 128.f);
  float d0 = v0 - m, d1 = v1 - m;
  float q = d0 * d0 + d1 * d1;
  #pragma unroll
  for (int off = 32; off; off >>= 1) q += __shfl_xor(q, off);
  float rs = rsqrtf(q * (1.f / 128.f) + 1e-5f);
  H[r * 128 + lane]      = d0 * rs * g[lane] + b[lane];
  H[r * 128 + 64 + lane] = d1 * rs * g[64 + lane] + b[64 + lane];
}

// ============================================================
// k_gemm: C = act(A[2048,K] @ W[N,K]^T + bias) (+R). 64x64 tile, 4x4 micro.
// blockIdx.z selects among up to 3 (W,bias,C) triples (QKV batching).
// ============================================================
__global__ __launch_bounds__(256) void k_gemm(const float* __restrict__ A,
                                              const float* __restrict__ W0, const float* __restrict__ W1, const float* __restrict__ W2,
                                              const float* __restrict__ b0, const float* __restrict__ b1, const float* __restrict__ b2,
                                              float* __restrict__ C0, float* __restrict__ C1, float* __restrict__ C2,
                                              const float* __restrict__ R, int N, int K, int act) {
  const float* W = (blockIdx.z == 0) ? W0 : (blockIdx.z == 1) ? W1 : W2;
  const float* bias = (blockIdx.z == 0) ? b0 : (blockIdx.z == 1) ? b1 : b2;
  float* C = (blockIdx.z == 0) ? C0 : (blockIdx.z == 1) ? C1 : C2;
  __shared__ float As[16][68];
  __shared__ float Ws[16][68];
  int tid = threadIdx.x;
  int tx = tid & 15, ty = tid >> 4;
  int m0 = blockIdx.x * 64, n0 = blockIdx.y * 64;
  int lr = tid >> 2, lk = (tid & 3) * 4;
  float acc[4][4] = {};
  for (int k0 = 0; k0 < K; k0 += 16) {
    float4 av = *(const float4*)(A + (m0 + lr) * K + k0 + lk);
    As[lk + 0][lr] = av.x; As[lk + 1][lr] = av.y; As[lk + 2][lr] = av.z; As[lk + 3][lr] = av.w;
    float4 wv = *(const float4*)(W + (n0 + lr) * K + k0 + lk);
    Ws[lk + 0][lr] = wv.x; Ws[lk + 1][lr] = wv.y;
    Ws[lk + 2][lr] = wv.z; Ws[lk + 3][lr] = wv.w;
    __syncthreads();
    #pragma unroll
    for (int kk = 0; kk < 16; kk++) {
      float a[4], bv[4];
      #pragma unroll
      for (int i = 0; i < 4; i++) a[i] = As[kk][ty * 4 + i];
      #pragma unroll
      for (int j = 0; j < 4; j++) bv[j] = Ws[kk][tx * 4 + j];
      #pragma unroll
      for (int i = 0; i < 4; i++)
        #pragma unroll
        for (int j = 0; j < 4; j++)
          acc[i][j] = fmaf(a[i], bv[j], acc[i][j]);
    }
    __syncthreads();
  }
  #pragma unroll
  for (int i = 0; i < 4; i++) {
    int m = m0 + ty * 4 + i;
    #pragma unroll
    for (int j = 0; j < 4; j++) {
      int n = n0 + tx * 4 + j;
      float v = acc[i][j] + bias[n];
      if (act == 1) v = geluf(v);
      if (R) v += R[m * N + n];
      C[m * N + n] = v;
    }
  }
}

// ============================================================
// k_attn: per (batch-row bb, head h). n=64, dh=16, scale 0.25. grid (32,8).
// ============================================================
__global__ __launch_bounds__(64) void k_attn(const float* __restrict__ Q, const float* __restrict__ K,
                                             const float* __restrict__ V, float* __restrict__ AO) {
  __shared__ float Ks[1024], Vs[1024], Ss[64 * 65];
  int bb = blockIdx.x, h = blockIdx.y, lane = threadIdx.x;
  int base = (bb * 64) * 128 + h * 16;
  for (int idx = lane; idx < 1024; idx += 64) {
    int n = idx >> 4, j = idx & 15;
    Ks[idx] = K[base + n * 128 + j];
    Vs[idx] = V[base + n * 128 + j];
  }
  __syncthreads();
  float q[16];
  #pragma unroll
  for (int j = 0; j < 16; j++) q[j] = Q[base + lane * 128 + j];
  float mx = -1e30f;
  for (int k = 0; k < 64; k++) {
    float s = 0.f;
    #pragma unroll
    for (int j = 0; j < 16; j++) s = fmaf(q[j], Ks[k * 16 + j], s);
    s *= 0.25f;
    Ss[lane * 65 + k] = s;
    mx = fmaxf(mx, s);
  }
  float l = 0.f, o[16];
  #pragma unroll
  for (int j = 0; j < 16; j++) o[j] = 0.f;
  for (int k = 0; k < 64; k++) {
    float p = __expf(Ss[lane * 65 + k] - mx);
    l += p;
    #pragma unroll
    for (int j = 0; j < 16; j++) o[j] = fmaf(p, Vs[k * 16 + j], o[j]);
  }
  float inv = 1.f / l;
  #pragma unroll
  for (int j = 0; j < 16; j++) AO[base + lane * 128 + j] = o[j] * inv;
}

// ============================================================
// k_head: 2-tap conv + bn3 + elu, then classifier. grid 16 (b).
// ============================================================
__global__ __launch_bounds__(256) void k_head(const float* __restrict__ X, const float* __restrict__ ew,
                                              const float* __restrict__ eb, const float* __restrict__ g3,
                                              const float* __restrict__ b3, const float* __restrict__ cw,
                                              const float* __restrict__ cb, float* __restrict__ out) {
  __shared__ float gbuf[8192];
  __shared__ float red[256];
  int b = blockIdx.x, tid = threadIdx.x;
  for (int idx = tid; idx < 8192; idx += 256) {
    int oc = idx >> 7, w = idx & 127;
    float a = 0.f;
    #pragma unroll 8
    for (int ic = 0; ic < 64; ic++) {
      a = fmaf(ew[(oc * 64 + ic) * 2 + 0], X[(b * 64 + ic) * 128 + w], a);
      a = fmaf(ew[(oc * 64 + ic) * 2 + 1], X[((16 + b) * 64 + ic) * 128 + w], a);
    }
    a += eb[oc];
    float v = a * (g3[oc] * BN_S) + b3[oc];
    gbuf[idx] = eluf(v);
  }
  __syncthreads();
  for (int c = 0; c < 4; c++) {
    float p = 0.f;
    for (int idx = tid; idx < 8192; idx += 256) p = fmaf(gbuf[idx], cw[c * 8192 + idx], p);
    red[tid] = p;
    __syncthreads();
    for (int s = 128; s > 0; s >>= 1) {
      if (tid < s) red[tid] += red[tid + s];
      __syncthreads();
    }
    if (tid == 0) out[b * 4 + c] = red[0] + cb[c];
    __syncthreads();
  }
}

// ============================================================
extern "C" void kernel_launch(void* const* d_in, const int* in_sizes, int n_in,
                              void* d_out, int out_size, void* d_ws, size_t ws_size,
                              hipStream_t stream) {
  const float* x    = (const float*)d_in[0];
  const float* tw1  = (const float*)d_in[1];  const float* tb1 = (const float*)d_in[2];
  const float* tw2  = (const float*)d_in[3];  const float* tb2 = (const float*)d_in[4];
  const float* tw3  = (const float*)d_in[5];  const float* tb3 = (const float*)d_in[6];
  const float* tw4  = (const float*)d_in[7];  const float* tb4 = (const float*)d_in[8];
  const float* bn1g = (const float*)d_in[9];  const float* bn1b = (const float*)d_in[10];
  const float* sw   = (const float*)d_in[11]; const float* sb   = (const float*)d_in[12];
  const float* bn2g = (const float*)d_in[13]; const float* bn2b = (const float*)d_in[14];
  const float* ln1g = (const float*)d_in[15]; const float* ln1b = (const float*)d_in[16];
  const float* ln2g = (const float*)d_in[17]; const float* ln2b = (const float*)d_in[18];
  const float* wq   = (const float*)d_in[19]; const float* bq   = (const float*)d_in[20];
  const float* wk   = (const float*)d_in[21]; const float* bk   = (const float*)d_in[22];
  const float* wv   = (const float*)d_in[23]; const float* bv   = (const float*)d_in[24];
  const float* wo   = (const float*)d_in[25]; const float* bo   = (const float*)d_in[26];
  const float* f1w  = (const float*)d_in[27]; const float* f1b  = (const float*)d_in[28];
  const float* f2w  = (const float*)d_in[29]; const float* f2b  = (const float*)d_in[30];
  const float* ew   = (const float*)d_in[31]; const float* eb   = (const float*)d_in[32];
  const float* g3   = (const float*)d_in[33]; const float* b3   = (const float*)d_in[34];
  const float* cw   = (const float*)d_in[35]; const float* cb   = (const float*)d_in[36];

  float* ws      = (float*)d_ws;
  float* tws1    = ws;               // 8320
  float* c1      = ws + 8320;        // 128
  float* biasEff = ws + 8448;        // 128
  u16*   Wb      = (u16*)(ws + 8576);// 532480 bf16 [u][o][kh] (1.04 MB)
  float* z       = ws + 541056;      // 2048000 [b][o][t]
  float* X       = ws + 2589056;     // 262144  [2048][128]
  float* H       = ws + 2851200;     // 262144
  float* Qb      = ws + 3113344;     // 262144
  float* Kb      = ws + 3375488;     // 262144
  float* Vb      = ws + 3637632;     // 262144
  float* AO      = ws + 3899776;     // 262144
  float* F1      = ws + 4161920;     // 1048576 [2048][512]

  k_tws1<<<33, 256, 0, stream>>>(tw1, tw2, tw3, tw4, tb1, tb2, tb3, tb4, bn1g, bn1b, tws1, c1);
  k_weff<<<128, 256, 0, stream>>>(sw, sb, tws1, c1, Wb, biasEff);
  k_conv<<<dim3(16, 2, 16), 256, 0, stream>>>(x, Wb, biasEff, bn2g, bn2b, z);
  k_pool<<<dim3(64, 16), 128, 0, stream>>>(z, X);

  for (int l = 0; l < 4; l++) {
    const float* WQ = wq + l * 16384; const float* WK = wk + l * 16384; const float* WV = wv + l * 16384;
    k_ln<<<512, 256, 0, stream>>>(X, H, ln1g + l * 128, ln1b + l * 128);
    k_gemm<<<dim3(32, 2, 3), 256, 0, stream>>>(H, WQ, WK, WV,
                                               bq + l * 128, bk + l * 128, bv + l * 128,
                                               Qb, Kb, Vb, nullptr, 128, 128, 0);
    k_attn<<<dim3(32, 8), 64, 0, stream>>>(Qb, Kb, Vb, AO);
    k_gemm<<<dim3(32, 2, 1), 256, 0, stream>>>(AO, wo + l * 16384, nullptr, nullptr,
                                               bo + l * 128, nullptr, nullptr,
                                               X, nullptr, nullptr, X, 128, 128, 0);
    k_ln<<<512, 256, 0, stream>>>(X, H, ln2g + l * 128, ln2b + l * 128);
    k_gemm<<<dim3(32, 8, 1), 256, 0, stream>>>(H, f1w + l * 65536, nullptr, nullptr,
                                               f1b + l * 512, nullptr, nullptr,
                                               F1, nullptr, nullptr, nullptr, 512, 128, 1);
    k_gemm<<<dim3(32, 2, 1), 256, 0, stream>>>(F1, f2w + l * 65536, nullptr, nullptr,
                                               f2b + l * 128, nullptr, nullptr,
                                               X, nullptr, nullptr, X, 128, 512, 0);
  }

  k_head<<<16, 256, 0, stream>>>(X, ew, eb, g3, b3, cw, cb, (float*)d_out);
}

// Round 5
// 613.199 us; speedup vs baseline: 1.6635x; 1.1839x over previous
//
#include <hip/hip_runtime.h>
#include <math.h>

typedef unsigned short u16;
typedef __attribute__((ext_vector_type(8))) short frag8;   // 8 bf16 = 4 VGPR
typedef __attribute__((ext_vector_type(4))) float f32x4;   // MFMA acc

__device__ __forceinline__ float eluf(float v) { return v > 0.f ? v : expm1f(v); }
__device__ __forceinline__ float geluf(float v) {
  return 0.5f * v * (1.f + erff(v * 0.70710678118654752f));
}
__device__ __forceinline__ u16 f2bf(float f) {
  union { float f; unsigned int i; } v; v.f = f;
  return (u16)((v.i + 0x7fffu + ((v.i >> 16) & 1u)) >> 16);
}

#define BN_S 0.99999500003749969f   /* 1/sqrt(1+1e-5) */

// ============================================================
// k_tws1: tws1[i][u] = s1[i] * tw_g[i%32][u-32+P_g]  (0 outside window)
//         c1[i]     = s1[i]*tb[i] + bn1_b[i]
// ============================================================
__global__ void k_tws1(const float* tw1, const float* tw2, const float* tw3, const float* tw4,
                       const float* tb1, const float* tb2, const float* tb3, const float* tb4,
                       const float* bn1g, const float* bn1b,
                       float* tws1, float* c1) {
  int idx = blockIdx.x * 256 + threadIdx.x;
  if (idx < 8320) {
    int i = idx / 65, u = idx - i * 65;
    int g = i >> 5, il = i & 31;
    const float* tws[4] = {tw1, tw2, tw3, tw4};
    const int P[4] = {7, 12, 25, 32};
    int c = u - 32;
    float s1 = bn1g[i] * BN_S;
    float val = 0.f;
    int p = P[g];
    if (c >= -p && c <= p) val = s1 * tws[g][il * (2 * p + 1) + (c + p)];
    tws1[idx] = val;
  } else if (idx < 8448) {
    int i = idx - 8320;
    int g = i >> 5, il = i & 31;
    const float* tbs[4] = {tb1, tb2, tb3, tb4};
    float s1 = bn1g[i] * BN_S;
    c1[i] = s1 * tbs[g][il] + bn1b[i];
  }
}

// ============================================================
// k_weff: Wb[u][o][kh] (bf16) = sum_i sw[o,i,kh] * tws1[i][u]
//         biasEff[o] = sb[o] + sum_{i,kh} sw[o,i,kh]*c1[i]
// ============================================================
__global__ __launch_bounds__(256) void k_weff(const float* __restrict__ sw, const float* __restrict__ sb,
                                              const float* __restrict__ tws1, const float* __restrict__ c1,
                                              u16* __restrict__ Wb, float* __restrict__ biasEff) {
  __shared__ float swl[8192];   // 32 KB: sw[o][i][kh]
  __shared__ float red[256];
  int o = blockIdx.x, tid = threadIdx.x;
  const float* swo = sw + o * 8192;
  for (int j = tid; j < 8192; j += 256) swl[j] = swo[j];
  __syncthreads();
  for (int idx = tid; idx < 4160; idx += 256) {
    int kh = idx / 65, u = idx - kh * 65;
    float a = 0.f;
    #pragma unroll 4
    for (int i = 0; i < 128; i++)
      a = fmaf(swl[i * 64 + kh], tws1[i * 65 + u], a);
    Wb[(u * 128 + o) * 64 + kh] = f2bf(a);
  }
  float pa = 0.f;
  for (int j = tid; j < 8192; j += 256)
    pa = fmaf(swl[j], c1[j >> 6], pa);
  red[tid] = pa;
  __syncthreads();
  for (int s = 128; s > 0; s >>= 1) {
    if (tid < s) red[tid] += red[tid + s];
    __syncthreads();
  }
  if (tid == 0) biasEff[o] = red[0] + sb[o];
}

// ============================================================
// k_conv (MFMA): z[b][o][t] = elu(bn2(conv)).  (unchanged from r4)
// ============================================================
__global__ __launch_bounds__(256) void k_conv(const float* __restrict__ x,
                                              const u16* __restrict__ Wb,
                                              const float* __restrict__ biasEff,
                                              const float* __restrict__ bn2g, const float* __restrict__ bn2b,
                                              float* __restrict__ z) {
  __shared__ u16 xs[128 * 88];   // 22.5 KB; row tt -> t0-32+tt, col kh
  const int tid = threadIdx.x;
  const int t0 = blockIdx.x * 64;
  const int o0 = blockIdx.y * 64;
  const int b  = blockIdx.z;

  #pragma unroll
  for (int i = 0; i < 8; i++) {
    int pos = tid + i * 256;
    int kh = pos >> 5;
    int tt = (pos & 31) * 4;
    int gt = t0 - 32 + tt;
    const float* xp = x + (b * 64 + kh) * 1000;
    float v[4];
    if (gt >= 0 && gt + 3 < 1000) {
      float4 f = *(const float4*)(xp + gt);
      v[0] = f.x; v[1] = f.y; v[2] = f.z; v[3] = f.w;
    } else {
      #pragma unroll
      for (int e = 0; e < 4; e++) { int g2 = gt + e; v[e] = (g2 >= 0 && g2 < 1000) ? xp[g2] : 0.f; }
    }
    #pragma unroll
    for (int e = 0; e < 4; e++) xs[(tt + e) * 88 + kh] = f2bf(v[e]);
  }
  __syncthreads();

  const int lane = tid & 63, wave = tid >> 6;
  const int wt = (wave & 1) * 32;
  const int wo = (wave >> 1) * 32;
  const int m = lane & 15, q = lane >> 4;

  f32x4 acc[2][2];
  #pragma unroll
  for (int i = 0; i < 2; i++)
    #pragma unroll
    for (int j = 0; j < 2; j++) acc[i][j] = (f32x4){0.f, 0.f, 0.f, 0.f};

  #pragma unroll 2
  for (int u = 0; u < 65; u++) {
    frag8 A[2][2], B[2][2];
    #pragma unroll
    for (int tp = 0; tp < 2; tp++)
      #pragma unroll
      for (int kc = 0; kc < 2; kc++)
        A[tp][kc] = *(const frag8*)&xs[(wt + tp * 16 + m + u) * 88 + kc * 32 + q * 8];
    #pragma unroll
    for (int op = 0; op < 2; op++)
      #pragma unroll
      for (int kc = 0; kc < 2; kc++)
        B[op][kc] = *(const frag8*)(Wb + ((u * 128) + o0 + wo + op * 16 + m) * 64 + kc * 32 + q * 8);
    #pragma unroll
    for (int tp = 0; tp < 2; tp++)
      #pragma unroll
      for (int op = 0; op < 2; op++) {
        acc[tp][op] = __builtin_amdgcn_mfma_f32_16x16x32_bf16(A[tp][0], B[op][0], acc[tp][op], 0, 0, 0);
        acc[tp][op] = __builtin_amdgcn_mfma_f32_16x16x32_bf16(A[tp][1], B[op][1], acc[tp][op], 0, 0, 0);
      }
  }

  #pragma unroll
  for (int op = 0; op < 2; op++) {
    int o = o0 + wo + op * 16 + m;
    float s2 = bn2g[o] * BN_S;
    float be = biasEff[o], b2 = bn2b[o];
    #pragma unroll
    for (int tp = 0; tp < 2; tp++) {
      #pragma unroll
      for (int r = 0; r < 4; r++) {
        int t = t0 + wt + tp * 16 + q * 4 + r;
        if (t < 1000)
          z[(b * 128 + o) * 1000 + t] = eluf((acc[tp][op][r] + be) * s2 + b2);
      }
    }
  }
}

// ============================================================
// k_pool: windows of 50, stride 15, npos=64. mean -> x1, log(var,ddof=1) -> x2.
// ============================================================
__global__ __launch_bounds__(128) void k_pool(const float* __restrict__ z, float* __restrict__ X) {
  int p = blockIdx.x, b = blockIdx.y, o = threadIdx.x;
  const float* zp = z + (b * 128 + o) * 1000 + p * 15;
  float s = 0.f, ss = 0.f;
  #pragma unroll
  for (int k = 0; k < 50; k++) { float v = zp[k]; s += v; ss = fmaf(v, v, ss); }
  float m = s * 0.02f;
  float var = (ss - s * m) * (1.f / 49.f);
  var = fminf(fmaxf(var, 1e-6f), 1e6f);
  X[(b * 64 + p) * 128 + o] = m;
  X[((16 + b) * 64 + p) * 128 + o] = logf(var);
}

// ============================================================
// k_ln: LayerNorm over d=128. 4 rows/block (one wave each).
// ============================================================
__global__ __launch_bounds__(256) void k_ln(const float* __restrict__ X, float* __restrict__ H,
                                            const float* __restrict__ g, const float* __restrict__ b) {
  int lane = threadIdx.x & 63;
  int r = blockIdx.x * 4 + (threadIdx.x >> 6);
  float v0 = X[r * 128 + lane], v1 = X[r * 128 + 64 + lane];
  float s = v0 + v1;
  #pragma unroll
  for (int off = 32; off; off >>= 1) s += __shfl_xor(s, off);
  float m = s * (1.f / 128.f);
  float d0 = v0 - m, d1 = v1 - m;
  float q = d0 * d0 + d1 * d1;
  #pragma unroll
  for (int off = 32; off; off >>= 1) q += __shfl_xor(q, off);
  float rs = rsqrtf(q * (1.f / 128.f) + 1e-5f);
  H[r * 128 + lane]      = d0 * rs * g[lane] + b[lane];
  H[r * 128 + 64 + lane] = d1 * rs * g[64 + lane] + b[64 + lane];
}

// ============================================================
// k_gemm: C = act(A[2048,K] @ W[N,K]^T + bias) (+R). 64x64 tile, 4x4 micro.
// blockIdx.z selects among up to 3 (W,bias,C) triples (QKV batching).
// ============================================================
__global__ __launch_bounds__(256) void k_gemm(const float* __restrict__ A,
                                              const float* __restrict__ W0, const float* __restrict__ W1, const float* __restrict__ W2,
                                              const float* __restrict__ b0, const float* __restrict__ b1, const float* __restrict__ b2,
                                              float* __restrict__ C0, float* __restrict__ C1, float* __restrict__ C2,
                                              const float* __restrict__ R, int N, int K, int act) {
  const float* W = (blockIdx.z == 0) ? W0 : (blockIdx.z == 1) ? W1 : W2;
  const float* bias = (blockIdx.z == 0) ? b0 : (blockIdx.z == 1) ? b1 : b2;
  float* C = (blockIdx.z == 0) ? C0 : (blockIdx.z == 1) ? C1 : C2;
  __shared__ float As[16][68];
  __shared__ float Ws[16][68];
  int tid = threadIdx.x;
  int tx = tid & 15, ty = tid >> 4;
  int m0 = blockIdx.x * 64, n0 = blockIdx.y * 64;
  int lr = tid >> 2, lk = (tid & 3) * 4;
  float acc[4][4] = {};
  for (int k0 = 0; k0 < K; k0 += 16) {
    float4 av = *(const float4*)(A + (m0 + lr) * K + k0 + lk);
    As[lk + 0][lr] = av.x; As[lk + 1][lr] = av.y; As[lk + 2][lr] = av.z; As[lk + 3][lr] = av.w;
    float4 wv = *(const float4*)(W + (n0 + lr) * K + k0 + lk);
    Ws[lk + 0][lr] = wv.x; Ws[lk + 1][lr] = wv.y;
    Ws[lk + 2][lr] = wv.z; Ws[lk + 3][lr] = wv.w;
    __syncthreads();
    #pragma unroll
    for (int kk = 0; kk < 16; kk++) {
      float a[4], bv[4];
      #pragma unroll
      for (int i = 0; i < 4; i++) a[i] = As[kk][ty * 4 + i];
      #pragma unroll
      for (int j = 0; j < 4; j++) bv[j] = Ws[kk][tx * 4 + j];
      #pragma unroll
      for (int i = 0; i < 4; i++)
        #pragma unroll
        for (int j = 0; j < 4; j++)
          acc[i][j] = fmaf(a[i], bv[j], acc[i][j]);
    }
    __syncthreads();
  }
  #pragma unroll
  for (int i = 0; i < 4; i++) {
    int m = m0 + ty * 4 + i;
    #pragma unroll
    for (int j = 0; j < 4; j++) {
      int n = n0 + tx * 4 + j;
      float v = acc[i][j] + bias[n];
      if (act == 1) v = geluf(v);
      if (R) v += R[m * N + n];
      C[m * N + n] = v;
    }
  }
}

// ============================================================
// k_attn: per (batch-row bb, head h). n=64, dh=16, scale 0.25. grid (32,8).
// ============================================================
__global__ __launch_bounds__(64) void k_attn(const float* __restrict__ Q, const float* __restrict__ K,
                                             const float* __restrict__ V, float* __restrict__ AO) {
  __shared__ float Ks[1024], Vs[1024], Ss[64 * 65];
  int bb = blockIdx.x, h = blockIdx.y, lane = threadIdx.x;
  int base = (bb * 64) * 128 + h * 16;
  for (int idx = lane; idx < 1024; idx += 64) {
    int n = idx >> 4, j = idx & 15;
    Ks[idx] = K[base + n * 128 + j];
    Vs[idx] = V[base + n * 128 + j];
  }
  __syncthreads();
  float q[16];
  #pragma unroll
  for (int j = 0; j < 16; j++) q[j] = Q[base + lane * 128 + j];
  float mx = -1e30f;
  for (int k = 0; k < 64; k++) {
    float s = 0.f;
    #pragma unroll
    for (int j = 0; j < 16; j++) s = fmaf(q[j], Ks[k * 16 + j], s);
    s *= 0.25f;
    Ss[lane * 65 + k] = s;
    mx = fmaxf(mx, s);
  }
  float l = 0.f, o[16];
  #pragma unroll
  for (int j = 0; j < 16; j++) o[j] = 0.f;
  for (int k = 0; k < 64; k++) {
    float p = __expf(Ss[lane * 65 + k] - mx);
    l += p;
    #pragma unroll
    for (int j = 0; j < 16; j++) o[j] = fmaf(p, Vs[k * 16 + j], o[j]);
  }
  float inv = 1.f / l;
  #pragma unroll
  for (int j = 0; j < 16; j++) AO[base + lane * 128 + j] = o[j] * inv;
}

// ============================================================
// k_head1: 2-tap conv over streams + bn3 + elu -> G[b][oc][w].
// grid (16 b, 4 oc-tiles of 16), 256 threads (2 oc-groups x 128 w).
// X staged in LDS (64 KB); ew reads wave-uniform (scalarized).
// ============================================================
__global__ __launch_bounds__(256) void k_head1(const float* __restrict__ X, const float* __restrict__ ew,
                                               const float* __restrict__ eb, const float* __restrict__ g3,
                                               const float* __restrict__ b3, float* __restrict__ G) {
  __shared__ float Xs[2][8192];   // 64 KB: [stream][ic*128+w]
  int b = blockIdx.x, ot = blockIdx.y;
  int tid = threadIdx.x;
  {
    const float4* x1 = (const float4*)(X + b * 8192);
    const float4* x2 = (const float4*)(X + (16 + b) * 8192);
    float4* s1 = (float4*)&Xs[0][0];
    float4* s2 = (float4*)&Xs[1][0];
    for (int i = tid; i < 2048; i += 256) { s1[i] = x1[i]; s2[i] = x2[i]; }
  }
  __syncthreads();
  int w = tid & 127, og = tid >> 7;
  int oc0 = ot * 16 + og * 8;
  float a[8] = {};
  for (int ic = 0; ic < 64; ic++) {
    float x1v = Xs[0][ic * 128 + w], x2v = Xs[1][ic * 128 + w];
    #pragma unroll
    for (int j = 0; j < 8; j++) {
      a[j] = fmaf(ew[((oc0 + j) * 64 + ic) * 2 + 0], x1v, a[j]);
      a[j] = fmaf(ew[((oc0 + j) * 64 + ic) * 2 + 1], x2v, a[j]);
    }
  }
  #pragma unroll
  for (int j = 0; j < 8; j++) {
    int oc = oc0 + j;
    float v = (a[j] + eb[oc]) * (g3[oc] * BN_S) + b3[oc];
    G[(b * 64 + oc) * 128 + w] = eluf(v);
  }
}

// ============================================================
// k_head2: out[b][c] = G[b] . cw[c] + cb[c]. grid (16 b, 4 c), 256 threads.
// ============================================================
__global__ __launch_bounds__(256) void k_head2(const float* __restrict__ G, const float* __restrict__ cw,
                                               const float* __restrict__ cb, float* __restrict__ out) {
  __shared__ float red[256];
  int b = blockIdx.x, c = blockIdx.y, tid = threadIdx.x;
  const float4* g4 = (const float4*)(G + b * 8192);
  const float4* c4 = (const float4*)(cw + c * 8192);
  float p = 0.f;
  for (int i = tid; i < 2048; i += 256) {
    float4 g = g4[i], w = c4[i];
    p += g.x * w.x + g.y * w.y + g.z * w.z + g.w * w.w;
  }
  red[tid] = p;
  __syncthreads();
  for (int s = 128; s > 0; s >>= 1) {
    if (tid < s) red[tid] += red[tid + s];
    __syncthreads();
  }
  if (tid == 0) out[b * 4 + c] = red[0] + cb[c];
}

// ============================================================
extern "C" void kernel_launch(void* const* d_in, const int* in_sizes, int n_in,
                              void* d_out, int out_size, void* d_ws, size_t ws_size,
                              hipStream_t stream) {
  const float* x    = (const float*)d_in[0];
  const float* tw1  = (const float*)d_in[1];  const float* tb1 = (const float*)d_in[2];
  const float* tw2  = (const float*)d_in[3];  const float* tb2 = (const float*)d_in[4];
  const float* tw3  = (const float*)d_in[5];  const float* tb3 = (const float*)d_in[6];
  const float* tw4  = (const float*)d_in[7];  const float* tb4 = (const float*)d_in[8];
  const float* bn1g = (const float*)d_in[9];  const float* bn1b = (const float*)d_in[10];
  const float* sw   = (const float*)d_in[11]; const float* sb   = (const float*)d_in[12];
  const float* bn2g = (const float*)d_in[13]; const float* bn2b = (const float*)d_in[14];
  const float* ln1g = (const float*)d_in[15]; const float* ln1b = (const float*)d_in[16];
  const float* ln2g = (const float*)d_in[17]; const float* ln2b = (const float*)d_in[18];
  const float* wq   = (const float*)d_in[19]; const float* bq   = (const float*)d_in[20];
  const float* wk   = (const float*)d_in[21]; const float* bk   = (const float*)d_in[22];
  const float* wv   = (const float*)d_in[23]; const float* bv   = (const float*)d_in[24];
  const float* wo   = (const float*)d_in[25]; const float* bo   = (const float*)d_in[26];
  const float* f1w  = (const float*)d_in[27]; const float* f1b  = (const float*)d_in[28];
  const float* f2w  = (const float*)d_in[29]; const float* f2b  = (const float*)d_in[30];
  const float* ew   = (const float*)d_in[31]; const float* eb   = (const float*)d_in[32];
  const float* g3   = (const float*)d_in[33]; const float* b3   = (const float*)d_in[34];
  const float* cw   = (const float*)d_in[35]; const float* cb   = (const float*)d_in[36];

  float* ws      = (float*)d_ws;
  float* tws1    = ws;               // 8320
  float* c1      = ws + 8320;        // 128
  float* biasEff = ws + 8448;        // 128
  u16*   Wb      = (u16*)(ws + 8576);// 532480 bf16 [u][o][kh] (1.04 MB)
  float* z       = ws + 541056;      // 2048000 [b][o][t]; reused as G after pool
  float* X       = ws + 2589056;     // 262144  [2048][128]
  float* H       = ws + 2851200;     // 262144
  float* Qb      = ws + 3113344;     // 262144
  float* Kb      = ws + 3375488;     // 262144
  float* Vb      = ws + 3637632;     // 262144
  float* AO      = ws + 3899776;     // 262144
  float* F1      = ws + 4161920;     // 1048576 [2048][512]
  float* G       = z;                // 131072 [16][64][128] (z dead after k_pool)

  k_tws1<<<33, 256, 0, stream>>>(tw1, tw2, tw3, tw4, tb1, tb2, tb3, tb4, bn1g, bn1b, tws1, c1);
  k_weff<<<128, 256, 0, stream>>>(sw, sb, tws1, c1, Wb, biasEff);
  k_conv<<<dim3(16, 2, 16), 256, 0, stream>>>(x, Wb, biasEff, bn2g, bn2b, z);
  k_pool<<<dim3(64, 16), 128, 0, stream>>>(z, X);

  for (int l = 0; l < 4; l++) {
    const float* WQ = wq + l * 16384; const float* WK = wk + l * 16384; const float* WV = wv + l * 16384;
    k_ln<<<512, 256, 0, stream>>>(X, H, ln1g + l * 128, ln1b + l * 128);
    k_gemm<<<dim3(32, 2, 3), 256, 0, stream>>>(H, WQ, WK, WV,
                                               bq + l * 128, bk + l * 128, bv + l * 128,
                                               Qb, Kb, Vb, nullptr, 128, 128, 0);
    k_attn<<<dim3(32, 8), 64, 0, stream>>>(Qb, Kb, Vb, AO);
    k_gemm<<<dim3(32, 2, 1), 256, 0, stream>>>(AO, wo + l * 16384, nullptr, nullptr,
                                               bo + l * 128, nullptr, nullptr,
                                               X, nullptr, nullptr, X, 128, 128, 0);
    k_ln<<<512, 256, 0, stream>>>(X, H, ln2g + l * 128, ln2b + l * 128);
    k_gemm<<<dim3(32, 8, 1), 256, 0, stream>>>(H, f1w + l * 65536, nullptr, nullptr,
                                               f1b + l * 512, nullptr, nullptr,
                                               F1, nullptr, nullptr, nullptr, 512, 128, 1);
    k_gemm<<<dim3(32, 2, 1), 256, 0, stream>>>(F1, f2w + l * 65536, nullptr, nullptr,
                                               f2b + l * 128, nullptr, nullptr,
                                               X, nullptr, nullptr, X, 128, 512, 0);
  }

  k_head1<<<dim3(16, 4), 256, 0, stream>>>(X, ew, eb, g3, b3, G);
  k_head2<<<dim3(16, 4), 256, 0, stream>>>(G, cw, cb, (float*)d_out);
}

// Round 6
// 505.805 us; speedup vs baseline: 2.0167x; 1.2123x over previous
//
#include <hip/hip_runtime.h>
#include <math.h>

typedef unsigned short u16;
typedef __attribute__((ext_vector_type(8))) short frag8;   // 8 bf16 = 4 VGPR
typedef __attribute__((ext_vector_type(4))) float f32x4;   // MFMA acc

__device__ __forceinline__ float eluf(float v) { return v > 0.f ? v : expm1f(v); }
__device__ __forceinline__ float geluf(float v) {
  return 0.5f * v * (1.f + erff(v * 0.70710678118654752f));
}
__device__ __forceinline__ u16 f2bf(float f) {
  union { float f; unsigned int i; } v; v.f = f;
  return (u16)((v.i + 0x7fffu + ((v.i >> 16) & 1u)) >> 16);
}

#define BN_S 0.99999500003749969f   /* 1/sqrt(1+1e-5) */

// ============================================================
// k_tws1: tws1[i][u] = s1[i] * tw_g[i%32][u-32+P_g]  (0 outside window)
//         c1[i]     = s1[i]*tb[i] + bn1_b[i]
// ============================================================
__global__ void k_tws1(const float* tw1, const float* tw2, const float* tw3, const float* tw4,
                       const float* tb1, const float* tb2, const float* tb3, const float* tb4,
                       const float* bn1g, const float* bn1b,
                       float* tws1, float* c1) {
  int idx = blockIdx.x * 256 + threadIdx.x;
  if (idx < 8320) {
    int i = idx / 65, u = idx - i * 65;
    int g = i >> 5, il = i & 31;
    const float* tws[4] = {tw1, tw2, tw3, tw4};
    const int P[4] = {7, 12, 25, 32};
    int c = u - 32;
    float s1 = bn1g[i] * BN_S;
    float val = 0.f;
    int p = P[g];
    if (c >= -p && c <= p) val = s1 * tws[g][il * (2 * p + 1) + (c + p)];
    tws1[idx] = val;
  } else if (idx < 8448) {
    int i = idx - 8320;
    int g = i >> 5, il = i & 31;
    const float* tbs[4] = {tb1, tb2, tb3, tb4};
    float s1 = bn1g[i] * BN_S;
    c1[i] = s1 * tbs[g][il] + bn1b[i];
  }
}

// ============================================================
// k_weff: one WAVE per (u, o). lane = kh.
//   u<65:  Wb[(u*128+o)*64+kh] = bf16( sum_i sw[o,i,kh]*tws1[i,u] )
//   u==65: biasEff[o] = sb[o] + sum_{i,kh} sw[o,i,kh]*c1[i]
// sw reads coalesced (lane=kh contiguous); tws1/c1 wave-uniform (s_load);
// Wb writes contiguous 128B per wave. grid (66, 32) x 256 thr.
// ============================================================
__global__ __launch_bounds__(256) void k_weff(const float* __restrict__ sw, const float* __restrict__ sb,
                                              const float* __restrict__ tws1, const float* __restrict__ c1,
                                              u16* __restrict__ Wb, float* __restrict__ biasEff) {
  const int lane = threadIdx.x & 63, wave = threadIdx.x >> 6;
  const int u = blockIdx.x;
  const int o = blockIdx.y * 4 + wave;
  const float* swp = sw + o * 8192 + lane;     // + i*64
  if (u < 65) {
    const float* tp = tws1 + u;                // + i*65 (wave-uniform)
    float a0 = 0.f, a1 = 0.f, a2 = 0.f, a3 = 0.f;
    #pragma unroll 8
    for (int i = 0; i < 128; i += 4) {
      a0 = fmaf(swp[(i + 0) * 64], tp[(i + 0) * 65], a0);
      a1 = fmaf(swp[(i + 1) * 64], tp[(i + 1) * 65], a1);
      a2 = fmaf(swp[(i + 2) * 64], tp[(i + 2) * 65], a2);
      a3 = fmaf(swp[(i + 3) * 64], tp[(i + 3) * 65], a3);
    }
    Wb[(u * 128 + o) * 64 + lane] = f2bf((a0 + a1) + (a2 + a3));
  } else {
    float pa = 0.f;
    #pragma unroll 8
    for (int i = 0; i < 128; i++)
      pa = fmaf(swp[i * 64], c1[i], pa);
    #pragma unroll
    for (int off = 32; off; off >>= 1) pa += __shfl_xor(pa, off);
    if (lane == 0) biasEff[o] = pa + sb[o];
  }
}

// ============================================================
// k_conv (MFMA): z[b][o][t] = elu(bn2(conv)).  (unchanged from r4)
// ============================================================
__global__ __launch_bounds__(256) void k_conv(const float* __restrict__ x,
                                              const u16* __restrict__ Wb,
                                              const float* __restrict__ biasEff,
                                              const float* __restrict__ bn2g, const float* __restrict__ bn2b,
                                              float* __restrict__ z) {
  __shared__ u16 xs[128 * 88];   // 22.5 KB; row tt -> t0-32+tt, col kh
  const int tid = threadIdx.x;
  const int t0 = blockIdx.x * 64;
  const int o0 = blockIdx.y * 64;
  const int b  = blockIdx.z;

  #pragma unroll
  for (int i = 0; i < 8; i++) {
    int pos = tid + i * 256;
    int kh = pos >> 5;
    int tt = (pos & 31) * 4;
    int gt = t0 - 32 + tt;
    const float* xp = x + (b * 64 + kh) * 1000;
    float v[4];
    if (gt >= 0 && gt + 3 < 1000) {
      float4 f = *(const float4*)(xp + gt);
      v[0] = f.x; v[1] = f.y; v[2] = f.z; v[3] = f.w;
    } else {
      #pragma unroll
      for (int e = 0; e < 4; e++) { int g2 = gt + e; v[e] = (g2 >= 0 && g2 < 1000) ? xp[g2] : 0.f; }
    }
    #pragma unroll
    for (int e = 0; e < 4; e++) xs[(tt + e) * 88 + kh] = f2bf(v[e]);
  }
  __syncthreads();

  const int lane = tid & 63, wave = tid >> 6;
  const int wt = (wave & 1) * 32;
  const int wo = (wave >> 1) * 32;
  const int m = lane & 15, q = lane >> 4;

  f32x4 acc[2][2];
  #pragma unroll
  for (int i = 0; i < 2; i++)
    #pragma unroll
    for (int j = 0; j < 2; j++) acc[i][j] = (f32x4){0.f, 0.f, 0.f, 0.f};

  #pragma unroll 2
  for (int u = 0; u < 65; u++) {
    frag8 A[2][2], B[2][2];
    #pragma unroll
    for (int tp = 0; tp < 2; tp++)
      #pragma unroll
      for (int kc = 0; kc < 2; kc++)
        A[tp][kc] = *(const frag8*)&xs[(wt + tp * 16 + m + u) * 88 + kc * 32 + q * 8];
    #pragma unroll
    for (int op = 0; op < 2; op++)
      #pragma unroll
      for (int kc = 0; kc < 2; kc++)
        B[op][kc] = *(const frag8*)(Wb + ((u * 128) + o0 + wo + op * 16 + m) * 64 + kc * 32 + q * 8);
    #pragma unroll
    for (int tp = 0; tp < 2; tp++)
      #pragma unroll
      for (int op = 0; op < 2; op++) {
        acc[tp][op] = __builtin_amdgcn_mfma_f32_16x16x32_bf16(A[tp][0], B[op][0], acc[tp][op], 0, 0, 0);
        acc[tp][op] = __builtin_amdgcn_mfma_f32_16x16x32_bf16(A[tp][1], B[op][1], acc[tp][op], 0, 0, 0);
      }
  }

  #pragma unroll
  for (int op = 0; op < 2; op++) {
    int o = o0 + wo + op * 16 + m;
    float s2 = bn2g[o] * BN_S;
    float be = biasEff[o], b2 = bn2b[o];
    #pragma unroll
    for (int tp = 0; tp < 2; tp++) {
      #pragma unroll
      for (int r = 0; r < 4; r++) {
        int t = t0 + wt + tp * 16 + q * 4 + r;
        if (t < 1000)
          z[(b * 128 + o) * 1000 + t] = eluf((acc[tp][op][r] + be) * s2 + b2);
      }
    }
  }
}

// ============================================================
// k_pool: windows of 50, stride 15, npos=64. mean -> x1, log(var,ddof=1) -> x2.
// ============================================================
__global__ __launch_bounds__(128) void k_pool(const float* __restrict__ z, float* __restrict__ X) {
  int p = blockIdx.x, b = blockIdx.y, o = threadIdx.x;
  const float* zp = z + (b * 128 + o) * 1000 + p * 15;
  float s = 0.f, ss = 0.f;
  #pragma unroll
  for (int k = 0; k < 50; k++) { float v = zp[k]; s += v; ss = fmaf(v, v, ss); }
  float m = s * 0.02f;
  float var = (ss - s * m) * (1.f / 49.f);
  var = fminf(fmaxf(var, 1e-6f), 1e6f);
  X[(b * 64 + p) * 128 + o] = m;
  X[((16 + b) * 64 + p) * 128 + o] = logf(var);
}

// ============================================================
// k_mgemm (MFMA bf16): C = act(LN?(A)[2048,K] @ W[N,K]^T + bias) (+R)
// 64x64 tile, 4 waves (2x2 of 16x16x32), K staged in 128-chunks.
// Optional fused LayerNorm on A rows (requires K==128).
// W/bias/C selected by n0/nper (QKV batching). R stride = nper.
// ============================================================
__global__ __launch_bounds__(256) void k_mgemm(const float* __restrict__ A,
                                               const float* __restrict__ W0, const float* __restrict__ W1, const float* __restrict__ W2,
                                               const float* __restrict__ b0, const float* __restrict__ b1, const float* __restrict__ b2,
                                               float* __restrict__ C0, float* __restrict__ C1, float* __restrict__ C2,
                                               const float* __restrict__ R,
                                               const float* __restrict__ lng, const float* __restrict__ lnb,
                                               int nper, int K, int act) {
  __shared__ u16 As[64 * 136];   // 17.4 KB, bf16, row stride 136 (16B-aligned, odd in 16B units)
  __shared__ u16 Ws[64 * 136];
  __shared__ float mS[64], rS[64];
  const int tid = threadIdx.x;
  const int lane = tid & 63, wave = tid >> 6;
  const int m0 = blockIdx.x * 64;
  const int n0 = blockIdx.y * 64;
  const int which = n0 / nper;
  const int nloc = n0 % nper;
  const float* W = (which == 0) ? W0 : (which == 1) ? W1 : W2;
  const float* bias = (which == 0) ? b0 : (which == 1) ? b1 : b2;
  float* C = (which == 0) ? C0 : (which == 1) ? C1 : C2;

  if (lng) {   // row stats (K==128)
    #pragma unroll 1
    for (int rr = 0; rr < 16; rr++) {
      int r = wave * 16 + rr;
      const float* ap = A + (m0 + r) * 128;
      float v0 = ap[lane], v1 = ap[64 + lane];
      float s = v0 + v1;
      #pragma unroll
      for (int off = 32; off; off >>= 1) s += __shfl_xor(s, off);
      float mn = s * (1.f / 128.f);
      float d0 = v0 - mn, d1 = v1 - mn;
      float qq = d0 * d0 + d1 * d1;
      #pragma unroll
      for (int off = 32; off; off >>= 1) qq += __shfl_xor(qq, off);
      if (lane == 0) { mS[r] = mn; rS[r] = rsqrtf(qq * (1.f / 128.f) + 1e-5f); }
    }
  }

  const int m = lane & 15, q = lane >> 4;
  const int wt = (wave & 1) * 32, wn = (wave >> 1) * 32;
  f32x4 acc[2][2];
  #pragma unroll
  for (int i = 0; i < 2; i++)
    #pragma unroll
    for (int j = 0; j < 2; j++) acc[i][j] = (f32x4){0.f, 0.f, 0.f, 0.f};

  for (int k0 = 0; k0 < K; k0 += 128) {
    __syncthreads();
    #pragma unroll
    for (int i = 0; i < 8; i++) {
      int pos = tid + i * 256;
      int row = pos >> 5;
      int c4 = (pos & 31) * 4;
      float4 av = *(const float4*)(A + (m0 + row) * K + k0 + c4);
      if (lng) {
        float mn = mS[row], rs = rS[row];
        av.x = (av.x - mn) * rs * lng[c4 + 0] + lnb[c4 + 0];
        av.y = (av.y - mn) * rs * lng[c4 + 1] + lnb[c4 + 1];
        av.z = (av.z - mn) * rs * lng[c4 + 2] + lnb[c4 + 2];
        av.w = (av.w - mn) * rs * lng[c4 + 3] + lnb[c4 + 3];
      }
      u16* ap = As + row * 136 + c4;
      ap[0] = f2bf(av.x); ap[1] = f2bf(av.y); ap[2] = f2bf(av.z); ap[3] = f2bf(av.w);
      float4 wv = *(const float4*)(W + (nloc + row) * K + k0 + c4);
      u16* wp = Ws + row * 136 + c4;
      wp[0] = f2bf(wv.x); wp[1] = f2bf(wv.y); wp[2] = f2bf(wv.z); wp[3] = f2bf(wv.w);
    }
    __syncthreads();
    #pragma unroll
    for (int kc = 0; kc < 4; kc++) {
      frag8 Af[2], Bf[2];
      #pragma unroll
      for (int tp = 0; tp < 2; tp++)
        Af[tp] = *(const frag8*)&As[(wt + tp * 16 + m) * 136 + kc * 32 + q * 8];
      #pragma unroll
      for (int np = 0; np < 2; np++)
        Bf[np] = *(const frag8*)&Ws[(wn + np * 16 + m) * 136 + kc * 32 + q * 8];
      #pragma unroll
      for (int tp = 0; tp < 2; tp++)
        #pragma unroll
        for (int np = 0; np < 2; np++)
          acc[tp][np] = __builtin_amdgcn_mfma_f32_16x16x32_bf16(Af[tp], Bf[np], acc[tp][np], 0, 0, 0);
    }
  }

  // epilogue: C row = q*4+r, col = m  [m89 layout]
  #pragma unroll
  for (int np = 0; np < 2; np++) {
    int col = nloc + wn + np * 16 + m;
    float bv = bias[col];
    #pragma unroll
    for (int tp = 0; tp < 2; tp++) {
      #pragma unroll
      for (int r = 0; r < 4; r++) {
        int mrow = m0 + wt + tp * 16 + q * 4 + r;
        float v = acc[tp][np][r] + bv;
        if (act == 1) v = geluf(v);
        if (R) v += R[mrow * nper + col];
        C[mrow * nper + col] = v;
      }
    }
  }
}

// ============================================================
// k_attn: per (batch-row bb, head h). n=64, dh=16, scale 0.25. grid (32,8).
// ============================================================
__global__ __launch_bounds__(64) void k_attn(const float* __restrict__ Q, const float* __restrict__ K,
                                             const float* __restrict__ V, float* __restrict__ AO) {
  __shared__ float Ks[1024], Vs[1024], Ss[64 * 65];
  int bb = blockIdx.x, h = blockIdx.y, lane = threadIdx.x;
  int base = (bb * 64) * 128 + h * 16;
  for (int idx = lane; idx < 1024; idx += 64) {
    int n = idx >> 4, j = idx & 15;
    Ks[idx] = K[base + n * 128 + j];
    Vs[idx] = V[base + n * 128 + j];
  }
  __syncthreads();
  float q[16];
  #pragma unroll
  for (int j = 0; j < 16; j++) q[j] = Q[base + lane * 128 + j];
  float mx = -1e30f;
  for (int k = 0; k < 64; k++) {
    float s = 0.f;
    #pragma unroll
    for (int j = 0; j < 16; j++) s = fmaf(q[j], Ks[k * 16 + j], s);
    s *= 0.25f;
    Ss[lane * 65 + k] = s;
    mx = fmaxf(mx, s);
  }
  float l = 0.f, o[16];
  #pragma unroll
  for (int j = 0; j < 16; j++) o[j] = 0.f;
  for (int k = 0; k < 64; k++) {
    float p = __expf(Ss[lane * 65 + k] - mx);
    l += p;
    #pragma unroll
    for (int j = 0; j < 16; j++) o[j] = fmaf(p, Vs[k * 16 + j], o[j]);
  }
  float inv = 1.f / l;
  #pragma unroll
  for (int j = 0; j < 16; j++) AO[base + lane * 128 + j] = o[j] * inv;
}

// ============================================================
// k_head1: 2-tap conv over streams + bn3 + elu -> G[b][oc][w]. grid (16,4).
// ============================================================
__global__ __launch_bounds__(256) void k_head1(const float* __restrict__ X, const float* __restrict__ ew,
                                               const float* __restrict__ eb, const float* __restrict__ g3,
                                               const float* __restrict__ b3, float* __restrict__ G) {
  __shared__ float Xs[2][8192];   // 64 KB
  int b = blockIdx.x, ot = blockIdx.y;
  int tid = threadIdx.x;
  {
    const float4* x1 = (const float4*)(X + b * 8192);
    const float4* x2 = (const float4*)(X + (16 + b) * 8192);
    float4* s1 = (float4*)&Xs[0][0];
    float4* s2 = (float4*)&Xs[1][0];
    for (int i = tid; i < 2048; i += 256) { s1[i] = x1[i]; s2[i] = x2[i]; }
  }
  __syncthreads();
  int w = tid & 127, og = tid >> 7;
  int oc0 = ot * 16 + og * 8;
  float a[8] = {};
  for (int ic = 0; ic < 64; ic++) {
    float x1v = Xs[0][ic * 128 + w], x2v = Xs[1][ic * 128 + w];
    #pragma unroll
    for (int j = 0; j < 8; j++) {
      a[j] = fmaf(ew[((oc0 + j) * 64 + ic) * 2 + 0], x1v, a[j]);
      a[j] = fmaf(ew[((oc0 + j) * 64 + ic) * 2 + 1], x2v, a[j]);
    }
  }
  #pragma unroll
  for (int j = 0; j < 8; j++) {
    int oc = oc0 + j;
    float v = (a[j] + eb[oc]) * (g3[oc] * BN_S) + b3[oc];
    G[(b * 64 + oc) * 128 + w] = eluf(v);
  }
}

// ============================================================
// k_head2: out[b][c] = G[b] . cw[c] + cb[c]. grid (16,4).
// ============================================================
__global__ __launch_bounds__(256) void k_head2(const float* __restrict__ G, const float* __restrict__ cw,
                                               const float* __restrict__ cb, float* __restrict__ out) {
  __shared__ float red[256];
  int b = blockIdx.x, c = blockIdx.y, tid = threadIdx.x;
  const float4* g4 = (const float4*)(G + b * 8192);
  const float4* c4 = (const float4*)(cw + c * 8192);
  float p = 0.f;
  for (int i = tid; i < 2048; i += 256) {
    float4 g = g4[i], w = c4[i];
    p += g.x * w.x + g.y * w.y + g.z * w.z + g.w * w.w;
  }
  red[tid] = p;
  __syncthreads();
  for (int s = 128; s > 0; s >>= 1) {
    if (tid < s) red[tid] += red[tid + s];
    __syncthreads();
  }
  if (tid == 0) out[b * 4 + c] = red[0] + cb[c];
}

// ============================================================
extern "C" void kernel_launch(void* const* d_in, const int* in_sizes, int n_in,
                              void* d_out, int out_size, void* d_ws, size_t ws_size,
                              hipStream_t stream) {
  const float* x    = (const float*)d_in[0];
  const float* tw1  = (const float*)d_in[1];  const float* tb1 = (const float*)d_in[2];
  const float* tw2  = (const float*)d_in[3];  const float* tb2 = (const float*)d_in[4];
  const float* tw3  = (const float*)d_in[5];  const float* tb3 = (const float*)d_in[6];
  const float* tw4  = (const float*)d_in[7];  const float* tb4 = (const float*)d_in[8];
  const float* bn1g = (const float*)d_in[9];  const float* bn1b = (const float*)d_in[10];
  const float* sw   = (const float*)d_in[11]; const float* sb   = (const float*)d_in[12];
  const float* bn2g = (const float*)d_in[13]; const float* bn2b = (const float*)d_in[14];
  const float* ln1g = (const float*)d_in[15]; const float* ln1b = (const float*)d_in[16];
  const float* ln2g = (const float*)d_in[17]; const float* ln2b = (const float*)d_in[18];
  const float* wq   = (const float*)d_in[19]; const float* bq   = (const float*)d_in[20];
  const float* wk   = (const float*)d_in[21]; const float* bk   = (const float*)d_in[22];
  const float* wv   = (const float*)d_in[23]; const float* bv   = (const float*)d_in[24];
  const float* wo   = (const float*)d_in[25]; const float* bo   = (const float*)d_in[26];
  const float* f1w  = (const float*)d_in[27]; const float* f1b  = (const float*)d_in[28];
  const float* f2w  = (const float*)d_in[29]; const float* f2b  = (const float*)d_in[30];
  const float* ew   = (const float*)d_in[31]; const float* eb   = (const float*)d_in[32];
  const float* g3   = (const float*)d_in[33]; const float* b3   = (const float*)d_in[34];
  const float* cw   = (const float*)d_in[35]; const float* cb   = (const float*)d_in[36];

  float* ws      = (float*)d_ws;
  float* tws1    = ws;               // 8320
  float* c1      = ws + 8320;        // 128
  float* biasEff = ws + 8448;        // 128
  u16*   Wb      = (u16*)(ws + 8576);// 532480 bf16 [u][o][kh] (1.04 MB)
  float* z       = ws + 541056;      // 2048000 [b][o][t]; reused as G after pool
  float* X       = ws + 2589056;     // 262144  [2048][128]
  float* Qb      = ws + 3113344;     // 262144
  float* Kb      = ws + 3375488;     // 262144
  float* Vb      = ws + 3637632;     // 262144
  float* AO      = ws + 3899776;     // 262144
  float* F1      = ws + 4161920;     // 1048576 [2048][512]
  float* G       = z;                // 131072 (z dead after k_pool)

  k_tws1<<<33, 256, 0, stream>>>(tw1, tw2, tw3, tw4, tb1, tb2, tb3, tb4, bn1g, bn1b, tws1, c1);
  k_weff<<<dim3(66, 32), 256, 0, stream>>>(sw, sb, tws1, c1, Wb, biasEff);
  k_conv<<<dim3(16, 2, 16), 256, 0, stream>>>(x, Wb, biasEff, bn2g, bn2b, z);
  k_pool<<<dim3(64, 16), 128, 0, stream>>>(z, X);

  for (int l = 0; l < 4; l++) {
    // ln1 + QKV (fused)
    k_mgemm<<<dim3(32, 6), 256, 0, stream>>>(X, wq + l * 16384, wk + l * 16384, wv + l * 16384,
                                             bq + l * 128, bk + l * 128, bv + l * 128,
                                             Qb, Kb, Vb, nullptr,
                                             ln1g + l * 128, ln1b + l * 128, 128, 128, 0);
    k_attn<<<dim3(32, 8), 64, 0, stream>>>(Qb, Kb, Vb, AO);
    // O-proj + residual
    k_mgemm<<<dim3(32, 2), 256, 0, stream>>>(AO, wo + l * 16384, nullptr, nullptr,
                                             bo + l * 128, nullptr, nullptr,
                                             X, nullptr, nullptr, X,
                                             nullptr, nullptr, 128, 128, 0);
    // ln2 + FF1 + gelu (fused)
    k_mgemm<<<dim3(32, 8), 256, 0, stream>>>(X, f1w + l * 65536, nullptr, nullptr,
                                             f1b + l * 512, nullptr, nullptr,
                                             F1, nullptr, nullptr, nullptr,
                                             ln2g + l * 128, ln2b + l * 128, 512, 128, 1);
    // FF2 + residual
    k_mgemm<<<dim3(32, 2), 256, 0, stream>>>(F1, f2w + l * 65536, nullptr, nullptr,
                                             f2b + l * 128, nullptr, nullptr,
                                             X, nullptr, nullptr, X,
                                             nullptr, nullptr, 128, 512, 0);
  }

  k_head1<<<dim3(16, 4), 256, 0, stream>>>(X, ew, eb, g3, b3, G);
  k_head2<<<dim3(16, 4), 256, 0, stream>>>(G, cw, cb, (float*)d_out);
}